// Round 1
// baseline (862.856 us; speedup 1.0000x reference)
//
#include <hip/hip_runtime.h>

#define N_NODES 100000
#define N_EDGES 1600000
#define D 64
#define N_GRAPHS 64
#define D_LIN 256
#define D_OUT 128
#define BN_EPS 1e-5f

// ---------------- CSR build ----------------
__global__ void k_count(const int* __restrict__ dstA, int* __restrict__ deg) {
  int i = blockIdx.x * blockDim.x + threadIdx.x;
  int stride = gridDim.x * blockDim.x;
  for (; i < N_EDGES; i += stride) atomicAdd(&deg[dstA[i]], 1);
}

__global__ void k_blocksum(const int* __restrict__ deg, int* __restrict__ bsum) {
  __shared__ int s[256];
  int t = threadIdx.x, i = blockIdx.x * 256 + t;
  s[t] = (i < N_NODES) ? deg[i] : 0;
  __syncthreads();
  for (int off = 128; off > 0; off >>= 1) {
    if (t < off) s[t] += s[t + off];
    __syncthreads();
  }
  if (t == 0) bsum[blockIdx.x] = s[0];
}

__global__ void k_scanblocks(const int* __restrict__ bsum, int* __restrict__ boff, int nb) {
  __shared__ int s[512];
  int t = threadIdx.x;
  int v = (t < nb) ? bsum[t] : 0;
  s[t] = v;
  __syncthreads();
  for (int off = 1; off < 512; off <<= 1) {
    int u = (t >= off) ? s[t - off] : 0;
    __syncthreads();
    s[t] += u;
    __syncthreads();
  }
  if (t < nb) boff[t] = s[t] - v;  // exclusive
}

// deg may alias rowcur (each thread reads its own element before any write)
__global__ void k_scanfinal(const int* __restrict__ deg, const int* __restrict__ boff,
                            int* __restrict__ rowptr, int* __restrict__ rowcur) {
  __shared__ int s[256];
  int t = threadIdx.x, i = blockIdx.x * 256 + t;
  int d = (i < N_NODES) ? deg[i] : 0;
  s[t] = d;
  __syncthreads();
  for (int off = 1; off < 256; off <<= 1) {
    int u = (t >= off) ? s[t - off] : 0;
    __syncthreads();
    s[t] += u;
    __syncthreads();
  }
  if (i < N_NODES) {
    int v = boff[blockIdx.x] + s[t] - d;
    rowptr[i] = v;
    rowcur[i] = v;
  }
  if (i == 0) rowptr[N_NODES] = N_EDGES;
}

__global__ void k_fill(const int* __restrict__ srcA, const int* __restrict__ dstA,
                       int* __restrict__ rowcur, int* __restrict__ colidx) {
  int i = blockIdx.x * blockDim.x + threadIdx.x;
  int stride = gridDim.x * blockDim.x;
  for (; i < N_EDGES; i += stride) {
    int d = dstA[i];
    int pos = atomicAdd(&rowcur[d], 1);
    colidx[pos] = srcA[i];
  }
}

// ---------------- fused GIN conv layer ----------------
// block = 256 threads (4 waves), tile = 64 rows.
// phase1: gather  t = bn_relu(h_in[row]) + sum_{j->row} bn_relu(h_in[j])   -> sT (LDS)
// phase2: h1 = relu(t @ w1 + b1)                                           -> sH (LDS)
// phase3: h2 = h1 @ w2 + b2 -> h_out (+ per-column sum/sumsq atomics for BN)
template <int APPLY_BN, int EMIT_STATS>
__global__ __launch_bounds__(256) void k_conv(
    const float* __restrict__ h_in, const float* __restrict__ ss,
    const int* __restrict__ rowptr, const int* __restrict__ colidx,
    const float* __restrict__ w1, const float* __restrict__ b1,
    const float* __restrict__ w2, const float* __restrict__ b2,
    float* __restrict__ h_out, float* __restrict__ stats) {
  __shared__ float sT[64][68];
  __shared__ float sW1[64 * 64];
  __shared__ float sW2[64 * 64];
  __shared__ float sH[64][68];
  __shared__ float sB1[64], sB2[64];
  __shared__ float sSum[64], sSq[64];
  __shared__ float sScale[64], sShift[64];

  int tid = threadIdx.x;
  for (int i = tid; i < 1024; i += 256) {
    ((float4*)sW1)[i] = ((const float4*)w1)[i];
    ((float4*)sW2)[i] = ((const float4*)w2)[i];
  }
  if (tid < 64) {
    sB1[tid] = b1[tid];
    sB2[tid] = b2[tid];
    if (APPLY_BN) { sScale[tid] = ss[tid]; sShift[tid] = ss[64 + tid]; }
    if (EMIT_STATS) { sSum[tid] = 0.f; sSq[tid] = 0.f; }
  }
  __syncthreads();

  const int wave = tid >> 6, lane = tid & 63;
  const int row0 = blockIdx.x * 64;
  const float scl = APPLY_BN ? sScale[lane] : 1.f;
  const float sft = APPLY_BN ? sShift[lane] : 0.f;

  for (int rr = 0; rr < 16; ++rr) {
    const int r = wave * 16 + rr;
    const int row = row0 + r;
    float sum = 0.f;
    if (row < N_NODES) {
      float v = h_in[row * 64 + lane];
      if (APPLY_BN) v = fmaxf(0.f, fmaf(v, scl, sft));
      sum = v;
      const int e0 = rowptr[row], e1 = rowptr[row + 1];
      for (int base = e0; base < e1; base += 64) {
        const int cnt = min(64, e1 - base);
        const int cidx = (lane < cnt) ? colidx[base + lane] : 0;
        int j = 0;
        for (; j + 3 < cnt; j += 4) {
          int s0 = __builtin_amdgcn_readlane(cidx, j);
          int s1 = __builtin_amdgcn_readlane(cidx, j + 1);
          int s2 = __builtin_amdgcn_readlane(cidx, j + 2);
          int s3 = __builtin_amdgcn_readlane(cidx, j + 3);
          float v0 = h_in[s0 * 64 + lane];
          float v1 = h_in[s1 * 64 + lane];
          float v2 = h_in[s2 * 64 + lane];
          float v3 = h_in[s3 * 64 + lane];
          if (APPLY_BN) {
            v0 = fmaxf(0.f, fmaf(v0, scl, sft));
            v1 = fmaxf(0.f, fmaf(v1, scl, sft));
            v2 = fmaxf(0.f, fmaf(v2, scl, sft));
            v3 = fmaxf(0.f, fmaf(v3, scl, sft));
          }
          sum += v0 + v1 + v2 + v3;
        }
        for (; j < cnt; ++j) {
          int s0 = __builtin_amdgcn_readlane(cidx, j);
          float v0 = h_in[s0 * 64 + lane];
          if (APPLY_BN) v0 = fmaxf(0.f, fmaf(v0, scl, sft));
          sum += v0;
        }
      }
    }
    sT[r][lane] = sum;
  }
  __syncthreads();

  const int tc = tid & 15, tr = tid >> 4;  // cols 4*tc.., rows 4*tr..

  // ---- GEMM1: h1 = relu(t @ w1 + b1) ----
  {
    float acc[4][4];
#pragma unroll
    for (int i = 0; i < 4; ++i)
#pragma unroll
      for (int j = 0; j < 4; ++j) acc[i][j] = 0.f;
#pragma unroll 8
    for (int k = 0; k < 64; ++k) {
      const float4 b = *(const float4*)&sW1[k * 64 + 4 * tc];
#pragma unroll
      for (int i = 0; i < 4; ++i) {
        const float a = sT[4 * tr + i][k];
        acc[i][0] = fmaf(a, b.x, acc[i][0]);
        acc[i][1] = fmaf(a, b.y, acc[i][1]);
        acc[i][2] = fmaf(a, b.z, acc[i][2]);
        acc[i][3] = fmaf(a, b.w, acc[i][3]);
      }
    }
    const float4 bb = *(const float4*)&sB1[4 * tc];
#pragma unroll
    for (int i = 0; i < 4; ++i) {
      float4 h;
      h.x = fmaxf(acc[i][0] + bb.x, 0.f);
      h.y = fmaxf(acc[i][1] + bb.y, 0.f);
      h.z = fmaxf(acc[i][2] + bb.z, 0.f);
      h.w = fmaxf(acc[i][3] + bb.w, 0.f);
      *(float4*)&sH[4 * tr + i][4 * tc] = h;
    }
  }
  __syncthreads();

  // ---- GEMM2: h2 = h1 @ w2 + b2 ----
  {
    float acc[4][4];
#pragma unroll
    for (int i = 0; i < 4; ++i)
#pragma unroll
      for (int j = 0; j < 4; ++j) acc[i][j] = 0.f;
#pragma unroll 8
    for (int k = 0; k < 64; ++k) {
      const float4 b = *(const float4*)&sW2[k * 64 + 4 * tc];
#pragma unroll
      for (int i = 0; i < 4; ++i) {
        const float a = sH[4 * tr + i][k];
        acc[i][0] = fmaf(a, b.x, acc[i][0]);
        acc[i][1] = fmaf(a, b.y, acc[i][1]);
        acc[i][2] = fmaf(a, b.z, acc[i][2]);
        acc[i][3] = fmaf(a, b.w, acc[i][3]);
      }
    }
    const float4 bb = *(const float4*)&sB2[4 * tc];
    float p[4] = {0.f, 0.f, 0.f, 0.f}, q[4] = {0.f, 0.f, 0.f, 0.f};
#pragma unroll
    for (int i = 0; i < 4; ++i) {
      const int row = row0 + 4 * tr + i;
      float4 o;
      o.x = acc[i][0] + bb.x;
      o.y = acc[i][1] + bb.y;
      o.z = acc[i][2] + bb.z;
      o.w = acc[i][3] + bb.w;
      if (row < N_NODES) {
        *(float4*)&h_out[row * 64 + 4 * tc] = o;
        if (EMIT_STATS) {
          p[0] += o.x; q[0] += o.x * o.x;
          p[1] += o.y; q[1] += o.y * o.y;
          p[2] += o.z; q[2] += o.z * o.z;
          p[3] += o.w; q[3] += o.w * o.w;
        }
      }
    }
    if (EMIT_STATS) {
#pragma unroll
      for (int j = 0; j < 4; ++j) {
        atomicAdd(&sSum[4 * tc + j], p[j]);
        atomicAdd(&sSq[4 * tc + j], q[j]);
      }
      __syncthreads();
      if (tid < 64) {
        atomicAdd(&stats[tid], sSum[tid]);
        atomicAdd(&stats[64 + tid], sSq[tid]);
      }
    }
  }
}

__global__ void k_bnfin(const float* __restrict__ stats, const float* __restrict__ gamma,
                        const float* __restrict__ beta, float* __restrict__ ss) {
  int t = threadIdx.x;
  if (t < 64) {
    const float inv_n = 1.f / (float)N_NODES;
    float mean = stats[t] * inv_n;
    float var = stats[64 + t] * inv_n - mean * mean;
    float scale = gamma[t] * rsqrtf(var + BN_EPS);
    ss[t] = scale;
    ss[64 + t] = beta[t] - mean * scale;
  }
}

// ---------------- global add pool (batch sorted) ----------------
__global__ __launch_bounds__(256) void k_pool(const float* __restrict__ h,
                                              const int* __restrict__ batch,
                                              float* __restrict__ emb) {
  const int NW = 1024;  // total waves
  const int RPW = (N_NODES + NW - 1) / NW;
  int wid = (blockIdx.x * 256 + threadIdx.x) >> 6;
  int lane = threadIdx.x & 63;
  int r0 = wid * RPW;
  if (r0 >= N_NODES) return;
  int r1 = min(r0 + RPW, N_NODES);
  float acc = 0.f;
  int curg = batch[r0];
  for (int i = r0; i < r1; ++i) {
    int g = batch[i];
    if (g != curg) {
      atomicAdd(&emb[curg * 64 + lane], acc);
      acc = 0.f;
      curg = g;
    }
    acc += h[i * 64 + lane];
  }
  atomicAdd(&emb[curg * 64 + lane], acc);
}

// ---------------- final MLP ----------------
__global__ __launch_bounds__(256) void k_mlp(const float* __restrict__ emb,
                                             const float* __restrict__ w1,
                                             const float* __restrict__ b1,
                                             const float* __restrict__ w2,
                                             const float* __restrict__ b2,
                                             float* __restrict__ out) {
  __shared__ float sp[64];
  __shared__ float smid[256];
  int g = blockIdx.x, t = threadIdx.x;
  if (t < 64) sp[t] = emb[g * 64 + t];
  __syncthreads();
  float acc = b1[t];
#pragma unroll 8
  for (int k = 0; k < 64; ++k) acc = fmaf(sp[k], w1[k * 256 + t], acc);
  smid[t] = fmaxf(acc, 0.f);
  __syncthreads();
  if (t < 128) {
    float o = b2[t];
#pragma unroll 8
    for (int k = 0; k < 256; ++k) o = fmaf(smid[k], w2[k * 128 + t], o);
    out[g * 128 + t] = o;
  }
}

extern "C" void kernel_launch(void* const* d_in, const int* in_sizes, int n_in,
                              void* d_out, int out_size, void* d_ws, size_t ws_size,
                              hipStream_t stream) {
  const float* x = (const float*)d_in[0];
  const int* edge = (const int*)d_in[1];
  const int* batch = (const int*)d_in[2];
  const float* cw1[3] = {(const float*)d_in[3], (const float*)d_in[7], (const float*)d_in[11]};
  const float* cb1[3] = {(const float*)d_in[4], (const float*)d_in[8], (const float*)d_in[12]};
  const float* cw2[3] = {(const float*)d_in[5], (const float*)d_in[9], (const float*)d_in[13]};
  const float* cb2[3] = {(const float*)d_in[6], (const float*)d_in[10], (const float*)d_in[14]};
  const float* bng[2] = {(const float*)d_in[15], (const float*)d_in[17]};
  const float* bnb[2] = {(const float*)d_in[16], (const float*)d_in[18]};
  const float* mpw1 = (const float*)d_in[19];
  const float* mpb1 = (const float*)d_in[20];
  const float* mpw2 = (const float*)d_in[21];
  const float* mpb2 = (const float*)d_in[22];

  char* ws = (char*)d_ws;
  size_t off = 0;
  auto alloc = [&](size_t bytes) {
    void* p = ws + off;
    off = (off + bytes + 255) & ~(size_t)255;
    return p;
  };
  int* rowptr = (int*)alloc((N_NODES + 1) * sizeof(int));
  int* rowcur = (int*)alloc(N_NODES * sizeof(int));
  int* colidx = (int*)alloc(N_EDGES * sizeof(int));
  int* bsum = (int*)alloc(512 * sizeof(int));
  int* boff = (int*)alloc(512 * sizeof(int));
  float* hA = (float*)alloc((size_t)N_NODES * 64 * sizeof(float));
  float* hB = (float*)alloc((size_t)N_NODES * 64 * sizeof(float));
  float* stats = (float*)alloc(2 * 128 * sizeof(float));
  float* ssbuf = (float*)alloc(2 * 128 * sizeof(float));

  float* outp = (float*)d_out;
  float* emb = outp + N_GRAPHS * D_OUT;  // output 1 lives right after output 0

  const int* srcA = edge;
  const int* dstA = edge + N_EDGES;

  hipMemsetAsync(rowcur, 0, N_NODES * sizeof(int), stream);
  hipMemsetAsync(stats, 0, 2 * 128 * sizeof(float), stream);
  hipMemsetAsync(emb, 0, N_GRAPHS * 64 * sizeof(float), stream);

  const int NB = (N_NODES + 255) / 256;  // 391
  k_count<<<2048, 256, 0, stream>>>(dstA, rowcur);
  k_blocksum<<<NB, 256, 0, stream>>>(rowcur, bsum);
  k_scanblocks<<<1, 512, 0, stream>>>(bsum, boff, NB);
  k_scanfinal<<<NB, 256, 0, stream>>>(rowcur, boff, rowptr, rowcur);
  k_fill<<<2048, 256, 0, stream>>>(srcA, dstA, rowcur, colidx);

  const int GC = (N_NODES + 63) / 64;  // 1563
  // layer 0: input x (no BN on input), emit stats0
  k_conv<0, 1><<<GC, 256, 0, stream>>>(x, nullptr, rowptr, colidx, cw1[0], cb1[0], cw2[0],
                                       cb2[0], hA, stats);
  k_bnfin<<<1, 64, 0, stream>>>(stats, bng[0], bnb[0], ssbuf);
  // layer 1: input hA with BN0+relu applied on the fly, emit stats1
  k_conv<1, 1><<<GC, 256, 0, stream>>>(hA, ssbuf, rowptr, colidx, cw1[1], cb1[1], cw2[1],
                                       cb2[1], hB, stats + 128);
  k_bnfin<<<1, 64, 0, stream>>>(stats + 128, bng[1], bnb[1], ssbuf + 128);
  // layer 2: input hB with BN1+relu, no stats
  k_conv<1, 0><<<GC, 256, 0, stream>>>(hB, ssbuf + 128, rowptr, colidx, cw1[2], cb1[2],
                                       cw2[2], cb2[2], hA, nullptr);

  k_pool<<<256, 256, 0, stream>>>(hA, batch, emb);
  k_mlp<<<N_GRAPHS, 256, 0, stream>>>(emb, mpw1, mpb1, mpw2, mpb2, outp);
}

// Round 2
// 611.485 us; speedup vs baseline: 1.4111x; 1.4111x over previous
//
#include <hip/hip_runtime.h>

#define N_NODES 100000
#define N_EDGES 1600000
#define D 64
#define N_GRAPHS 64
#define D_LIN 256
#define D_OUT 128
#define BN_EPS 1e-5f

__device__ __forceinline__ float4 ld4(const float* p) { return *(const float4*)p; }

// ---------------- CSR build ----------------
__global__ void k_count(const int* __restrict__ dstA, int* __restrict__ deg) {
  int i = blockIdx.x * blockDim.x + threadIdx.x;
  if (i < N_EDGES) atomicAdd(&deg[dstA[i]], 1);
}

__global__ void k_blocksum(const int* __restrict__ deg, int* __restrict__ bsum) {
  __shared__ int s[256];
  int t = threadIdx.x, i = blockIdx.x * 256 + t;
  s[t] = (i < N_NODES) ? deg[i] : 0;
  __syncthreads();
  for (int off = 128; off > 0; off >>= 1) {
    if (t < off) s[t] += s[t + off];
    __syncthreads();
  }
  if (t == 0) bsum[blockIdx.x] = s[0];
}

__global__ void k_scanblocks(const int* __restrict__ bsum, int* __restrict__ boff, int nb) {
  __shared__ int s[512];
  int t = threadIdx.x;
  int v = (t < nb) ? bsum[t] : 0;
  s[t] = v;
  __syncthreads();
  for (int off = 1; off < 512; off <<= 1) {
    int u = (t >= off) ? s[t - off] : 0;
    __syncthreads();
    s[t] += u;
    __syncthreads();
  }
  if (t < nb) boff[t] = s[t] - v;  // exclusive
}

// deg may alias rowcur (each thread reads its own element before any write)
__global__ void k_scanfinal(const int* __restrict__ deg, const int* __restrict__ boff,
                            int* __restrict__ rowptr, int* __restrict__ rowcur) {
  __shared__ int s[256];
  int t = threadIdx.x, i = blockIdx.x * 256 + t;
  int d = (i < N_NODES) ? deg[i] : 0;
  s[t] = d;
  __syncthreads();
  for (int off = 1; off < 256; off <<= 1) {
    int u = (t >= off) ? s[t - off] : 0;
    __syncthreads();
    s[t] += u;
    __syncthreads();
  }
  if (i < N_NODES) {
    int v = boff[blockIdx.x] + s[t] - d;
    rowptr[i] = v;
    rowcur[i] = v;
  }
  if (i == 0) rowptr[N_NODES] = N_EDGES;
}

__global__ void k_fill(const int* __restrict__ srcA, const int* __restrict__ dstA,
                       int* __restrict__ rowcur, int* __restrict__ colidx) {
  int i = blockIdx.x * blockDim.x + threadIdx.x;
  if (i < N_EDGES) {
    int d = dstA[i];
    int pos = atomicAdd(&rowcur[d], 1);
    colidx[pos] = srcA[i];
  }
}

// ---------------- fused GIN conv layer ----------------
// block = 256 threads (4 waves), tile = 64 rows, LDS = 18 KB -> 8 blocks/CU.
// gather: lane = (eg = edge-group 0..3, c4 = 4-feature slot); 4 edges x float4
//         per wave-load (1 KB), cross-eg shuffle reduce per row.
// GEMM1/GEMM2: weights streamed from global (L1/L2-resident), one shared
//         sT buffer reused for t and h1.
template <int APPLY_BN, int EMIT_STATS>
__global__ __launch_bounds__(256, 8) void k_conv(
    const float* __restrict__ h_in, const float* __restrict__ ss,
    const int* __restrict__ rowptr, const int* __restrict__ colidx,
    const float* __restrict__ w1, const float* __restrict__ b1,
    const float* __restrict__ w2, const float* __restrict__ b2,
    float* __restrict__ h_out, float* __restrict__ stats) {
  __shared__ float sT[64][68];
  __shared__ float sSum[64], sSq[64];

  const int tid = threadIdx.x;
  const int wave = tid >> 6, lane = tid & 63;
  const int eg = lane >> 4;
  const int c4 = (lane & 15) << 2;
  const int row0 = blockIdx.x * 64;

  if (EMIT_STATS && tid < 64) { sSum[tid] = 0.f; sSq[tid] = 0.f; }

  float4 scl4 = {1.f, 1.f, 1.f, 1.f}, sft4 = {0.f, 0.f, 0.f, 0.f};
  if (APPLY_BN) { scl4 = ld4(&ss[c4]); sft4 = ld4(&ss[64 + c4]); }

#define BNRELU(v)                                    \
  if (APPLY_BN) {                                    \
    v.x = fmaxf(fmaf(v.x, scl4.x, sft4.x), 0.f);     \
    v.y = fmaxf(fmaf(v.y, scl4.y, sft4.y), 0.f);     \
    v.z = fmaxf(fmaf(v.z, scl4.z, sft4.z), 0.f);     \
    v.w = fmaxf(fmaf(v.w, scl4.w, sft4.w), 0.f);     \
  }

  // ---- phase 1: gather ----
  for (int rr = 0; rr < 16; ++rr) {
    const int r = (wave << 4) + rr;
    const int row = row0 + r;
    float4 acc = {0.f, 0.f, 0.f, 0.f};
    if (row < N_NODES) {  // wave-uniform
      if (eg == 0) {
        float4 v = ld4(&h_in[row * 64 + c4]);
        BNRELU(v);
        acc = v;
      }
      const int e0 = rowptr[row], e1 = rowptr[row + 1];
      int e = e0 + eg;
      for (; e + 4 < e1; e += 8) {
        int s0 = colidx[e];
        int s1 = colidx[e + 4];
        float4 v0 = ld4(&h_in[s0 * 64 + c4]);
        float4 v1 = ld4(&h_in[s1 * 64 + c4]);
        BNRELU(v0);
        BNRELU(v1);
        acc.x += v0.x + v1.x;
        acc.y += v0.y + v1.y;
        acc.z += v0.z + v1.z;
        acc.w += v0.w + v1.w;
      }
      if (e < e1) {
        int s0 = colidx[e];
        float4 v0 = ld4(&h_in[s0 * 64 + c4]);
        BNRELU(v0);
        acc.x += v0.x;
        acc.y += v0.y;
        acc.z += v0.z;
        acc.w += v0.w;
      }
      // reduce across the 4 edge-groups
      acc.x += __shfl_xor(acc.x, 16);
      acc.y += __shfl_xor(acc.y, 16);
      acc.z += __shfl_xor(acc.z, 16);
      acc.w += __shfl_xor(acc.w, 16);
      acc.x += __shfl_xor(acc.x, 32);
      acc.y += __shfl_xor(acc.y, 32);
      acc.z += __shfl_xor(acc.z, 32);
      acc.w += __shfl_xor(acc.w, 32);
    }
    if (eg == 0) *(float4*)&sT[r][c4] = acc;
  }
  __syncthreads();

  const int tc = tid & 15, tr = tid >> 4;  // output cols 4*tc.., rows 4*tr..

  // ---- GEMM1: h1 = relu(t @ w1 + b1), accumulate in regs, write back to sT ----
  float hreg[4][4];
  {
    float acc[4][4];
#pragma unroll
    for (int i = 0; i < 4; ++i)
#pragma unroll
      for (int j = 0; j < 4; ++j) acc[i][j] = 0.f;
#pragma unroll 8
    for (int k = 0; k < 64; ++k) {
      const float4 b = ld4(&w1[(k << 6) + (tc << 2)]);
#pragma unroll
      for (int i = 0; i < 4; ++i) {
        const float a = sT[(tr << 2) + i][k];
        acc[i][0] = fmaf(a, b.x, acc[i][0]);
        acc[i][1] = fmaf(a, b.y, acc[i][1]);
        acc[i][2] = fmaf(a, b.z, acc[i][2]);
        acc[i][3] = fmaf(a, b.w, acc[i][3]);
      }
    }
    const float4 bb = ld4(&b1[tc << 2]);
#pragma unroll
    for (int i = 0; i < 4; ++i) {
      hreg[i][0] = fmaxf(acc[i][0] + bb.x, 0.f);
      hreg[i][1] = fmaxf(acc[i][1] + bb.y, 0.f);
      hreg[i][2] = fmaxf(acc[i][2] + bb.z, 0.f);
      hreg[i][3] = fmaxf(acc[i][3] + bb.w, 0.f);
    }
  }
  __syncthreads();
#pragma unroll
  for (int i = 0; i < 4; ++i)
    *(float4*)&sT[(tr << 2) + i][tc << 2] = *(float4*)&hreg[i][0];
  __syncthreads();

  // ---- GEMM2: h2 = h1 @ w2 + b2 -> global (+ BN stats) ----
  {
    float acc[4][4];
#pragma unroll
    for (int i = 0; i < 4; ++i)
#pragma unroll
      for (int j = 0; j < 4; ++j) acc[i][j] = 0.f;
#pragma unroll 8
    for (int k = 0; k < 64; ++k) {
      const float4 b = ld4(&w2[(k << 6) + (tc << 2)]);
#pragma unroll
      for (int i = 0; i < 4; ++i) {
        const float a = sT[(tr << 2) + i][k];
        acc[i][0] = fmaf(a, b.x, acc[i][0]);
        acc[i][1] = fmaf(a, b.y, acc[i][1]);
        acc[i][2] = fmaf(a, b.z, acc[i][2]);
        acc[i][3] = fmaf(a, b.w, acc[i][3]);
      }
    }
    const float4 bb = ld4(&b2[tc << 2]);
    float p[4] = {0.f, 0.f, 0.f, 0.f}, q[4] = {0.f, 0.f, 0.f, 0.f};
#pragma unroll
    for (int i = 0; i < 4; ++i) {
      const int row = row0 + (tr << 2) + i;
      float4 o;
      o.x = acc[i][0] + bb.x;
      o.y = acc[i][1] + bb.y;
      o.z = acc[i][2] + bb.z;
      o.w = acc[i][3] + bb.w;
      if (row < N_NODES) {
        *(float4*)&h_out[row * 64 + (tc << 2)] = o;
        if (EMIT_STATS) {
          p[0] += o.x; q[0] += o.x * o.x;
          p[1] += o.y; q[1] += o.y * o.y;
          p[2] += o.z; q[2] += o.z * o.z;
          p[3] += o.w; q[3] += o.w * o.w;
        }
      }
    }
    if (EMIT_STATS) {
#pragma unroll
      for (int j = 0; j < 4; ++j) {
        atomicAdd(&sSum[(tc << 2) + j], p[j]);
        atomicAdd(&sSq[(tc << 2) + j], q[j]);
      }
      __syncthreads();
      if (tid < 64) {
        atomicAdd(&stats[tid], sSum[tid]);
        atomicAdd(&stats[64 + tid], sSq[tid]);
      }
    }
  }
#undef BNRELU
}

__global__ void k_bnfin(const float* __restrict__ stats, const float* __restrict__ gamma,
                        const float* __restrict__ beta, float* __restrict__ ss) {
  int t = threadIdx.x;
  if (t < 64) {
    const float inv_n = 1.f / (float)N_NODES;
    float mean = stats[t] * inv_n;
    float var = stats[64 + t] * inv_n - mean * mean;
    float scale = gamma[t] * rsqrtf(var + BN_EPS);
    ss[t] = scale;
    ss[64 + t] = beta[t] - mean * scale;
  }
}

// ---------------- global add pool (batch sorted) ----------------
__global__ __launch_bounds__(256) void k_pool(const float* __restrict__ h,
                                              const int* __restrict__ batch,
                                              float* __restrict__ emb) {
  const int NW = 1024;  // total waves
  const int RPW = (N_NODES + NW - 1) / NW;
  int wid = (blockIdx.x * 256 + threadIdx.x) >> 6;
  int lane = threadIdx.x & 63;
  int r0 = wid * RPW;
  if (r0 >= N_NODES) return;
  int r1 = min(r0 + RPW, N_NODES);
  float acc = 0.f;
  int curg = batch[r0];
  for (int i = r0; i < r1; ++i) {
    int g = batch[i];
    if (g != curg) {
      atomicAdd(&emb[curg * 64 + lane], acc);
      acc = 0.f;
      curg = g;
    }
    acc += h[i * 64 + lane];
  }
  atomicAdd(&emb[curg * 64 + lane], acc);
}

// ---------------- final MLP ----------------
__global__ __launch_bounds__(256) void k_mlp(const float* __restrict__ emb,
                                             const float* __restrict__ w1,
                                             const float* __restrict__ b1,
                                             const float* __restrict__ w2,
                                             const float* __restrict__ b2,
                                             float* __restrict__ out) {
  __shared__ float sp[64];
  __shared__ float smid[256];
  int g = blockIdx.x, t = threadIdx.x;
  if (t < 64) sp[t] = emb[g * 64 + t];
  __syncthreads();
  float acc = b1[t];
#pragma unroll 8
  for (int k = 0; k < 64; ++k) acc = fmaf(sp[k], w1[k * 256 + t], acc);
  smid[t] = fmaxf(acc, 0.f);
  __syncthreads();
  if (t < 128) {
    float o = b2[t];
#pragma unroll 8
    for (int k = 0; k < 256; ++k) o = fmaf(smid[k], w2[k * 128 + t], o);
    out[g * 128 + t] = o;
  }
}

extern "C" void kernel_launch(void* const* d_in, const int* in_sizes, int n_in,
                              void* d_out, int out_size, void* d_ws, size_t ws_size,
                              hipStream_t stream) {
  const float* x = (const float*)d_in[0];
  const int* edge = (const int*)d_in[1];
  const int* batch = (const int*)d_in[2];
  const float* cw1[3] = {(const float*)d_in[3], (const float*)d_in[7], (const float*)d_in[11]};
  const float* cb1[3] = {(const float*)d_in[4], (const float*)d_in[8], (const float*)d_in[12]};
  const float* cw2[3] = {(const float*)d_in[5], (const float*)d_in[9], (const float*)d_in[13]};
  const float* cb2[3] = {(const float*)d_in[6], (const float*)d_in[10], (const float*)d_in[14]};
  const float* bng[2] = {(const float*)d_in[15], (const float*)d_in[17]};
  const float* bnb[2] = {(const float*)d_in[16], (const float*)d_in[18]};
  const float* mpw1 = (const float*)d_in[19];
  const float* mpb1 = (const float*)d_in[20];
  const float* mpw2 = (const float*)d_in[21];
  const float* mpb2 = (const float*)d_in[22];

  char* ws = (char*)d_ws;
  size_t off = 0;
  auto alloc = [&](size_t bytes) {
    void* p = ws + off;
    off = (off + bytes + 255) & ~(size_t)255;
    return p;
  };
  int* rowptr = (int*)alloc((N_NODES + 1) * sizeof(int));
  int* rowcur = (int*)alloc(N_NODES * sizeof(int));
  int* colidx = (int*)alloc(N_EDGES * sizeof(int));
  int* bsum = (int*)alloc(512 * sizeof(int));
  int* boff = (int*)alloc(512 * sizeof(int));
  float* hA = (float*)alloc((size_t)N_NODES * 64 * sizeof(float));
  float* hB = (float*)alloc((size_t)N_NODES * 64 * sizeof(float));
  float* stats = (float*)alloc(2 * 128 * sizeof(float));
  float* ssbuf = (float*)alloc(2 * 128 * sizeof(float));

  float* outp = (float*)d_out;
  float* emb = outp + N_GRAPHS * D_OUT;  // output 1 lives right after output 0

  const int* srcA = edge;
  const int* dstA = edge + N_EDGES;

  hipMemsetAsync(rowcur, 0, N_NODES * sizeof(int), stream);
  hipMemsetAsync(stats, 0, 2 * 128 * sizeof(float), stream);
  hipMemsetAsync(emb, 0, N_GRAPHS * 64 * sizeof(float), stream);

  const int NB = (N_NODES + 255) / 256;   // 391
  const int EB = (N_EDGES + 255) / 256;   // 6250
  k_count<<<EB, 256, 0, stream>>>(dstA, rowcur);
  k_blocksum<<<NB, 256, 0, stream>>>(rowcur, bsum);
  k_scanblocks<<<1, 512, 0, stream>>>(bsum, boff, NB);
  k_scanfinal<<<NB, 256, 0, stream>>>(rowcur, boff, rowptr, rowcur);
  k_fill<<<EB, 256, 0, stream>>>(srcA, dstA, rowcur, colidx);

  const int GC = (N_NODES + 63) / 64;  // 1563
  // layer 0: input x (no BN on input), emit stats0
  k_conv<0, 1><<<GC, 256, 0, stream>>>(x, nullptr, rowptr, colidx, cw1[0], cb1[0], cw2[0],
                                       cb2[0], hA, stats);
  k_bnfin<<<1, 64, 0, stream>>>(stats, bng[0], bnb[0], ssbuf);
  // layer 1: input hA with BN0+relu applied on the fly, emit stats1
  k_conv<1, 1><<<GC, 256, 0, stream>>>(hA, ssbuf, rowptr, colidx, cw1[1], cb1[1], cw2[1],
                                       cb2[1], hB, stats + 128);
  k_bnfin<<<1, 64, 0, stream>>>(stats + 128, bng[1], bnb[1], ssbuf + 128);
  // layer 2: input hB with BN1+relu, no stats
  k_conv<1, 0><<<GC, 256, 0, stream>>>(hB, ssbuf + 128, rowptr, colidx, cw1[2], cb1[2],
                                       cw2[2], cb2[2], hA, nullptr);

  k_pool<<<256, 256, 0, stream>>>(hA, batch, emb);
  k_mlp<<<N_GRAPHS, 256, 0, stream>>>(emb, mpw1, mpb1, mpw2, mpb2, outp);
}

// Round 3
// 537.915 us; speedup vs baseline: 1.6041x; 1.1368x over previous
//
#include <hip/hip_runtime.h>

#define N_NODES 100000
#define N_EDGES 1600000
#define D 64
#define N_GRAPHS 64
#define D_LIN 256
#define D_OUT 128
#define BN_EPS 1e-5f

typedef unsigned short ushort;
typedef unsigned int uint;

__device__ __forceinline__ float4 ld4(const float* p) { return *(const float4*)p; }

__device__ __forceinline__ uint f2bf(float f) {
  uint u = __float_as_uint(f);
  return (u + 0x7FFFu + ((u >> 16) & 1u)) >> 16;  // RNE
}

// ---------------- x -> bf16 prepass ----------------
__global__ __launch_bounds__(256) void k_cvt(const float* __restrict__ in,
                                             ushort* __restrict__ out, int n8) {
  int i = blockIdx.x * 256 + threadIdx.x;
  if (i < n8) {
    float4 a = ((const float4*)in)[2 * i];
    float4 b = ((const float4*)in)[2 * i + 1];
    uint4 o;
    o.x = f2bf(a.x) | (f2bf(a.y) << 16);
    o.y = f2bf(a.z) | (f2bf(a.w) << 16);
    o.z = f2bf(b.x) | (f2bf(b.y) << 16);
    o.w = f2bf(b.z) | (f2bf(b.w) << 16);
    ((uint4*)out)[i] = o;
  }
}

// ---------------- CSR build ----------------
__global__ void k_count(const int* __restrict__ dstA, int* __restrict__ deg) {
  int i = blockIdx.x * blockDim.x + threadIdx.x;
  if (i < N_EDGES) atomicAdd(&deg[dstA[i]], 1);
}

__global__ void k_blocksum(const int* __restrict__ deg, int* __restrict__ bsum) {
  __shared__ int s[256];
  int t = threadIdx.x, i = blockIdx.x * 256 + t;
  s[t] = (i < N_NODES) ? deg[i] : 0;
  __syncthreads();
  for (int off = 128; off > 0; off >>= 1) {
    if (t < off) s[t] += s[t + off];
    __syncthreads();
  }
  if (t == 0) bsum[blockIdx.x] = s[0];
}

__global__ void k_scanblocks(const int* __restrict__ bsum, int* __restrict__ boff, int nb) {
  __shared__ int s[512];
  int t = threadIdx.x;
  int v = (t < nb) ? bsum[t] : 0;
  s[t] = v;
  __syncthreads();
  for (int off = 1; off < 512; off <<= 1) {
    int u = (t >= off) ? s[t - off] : 0;
    __syncthreads();
    s[t] += u;
    __syncthreads();
  }
  if (t < nb) boff[t] = s[t] - v;  // exclusive
}

// deg may alias rowcur (each thread reads its own element before any write)
__global__ void k_scanfinal(const int* __restrict__ deg, const int* __restrict__ boff,
                            int* __restrict__ rowptr, int* __restrict__ rowcur) {
  __shared__ int s[256];
  int t = threadIdx.x, i = blockIdx.x * 256 + t;
  int d = (i < N_NODES) ? deg[i] : 0;
  s[t] = d;
  __syncthreads();
  for (int off = 1; off < 256; off <<= 1) {
    int u = (t >= off) ? s[t - off] : 0;
    __syncthreads();
    s[t] += u;
    __syncthreads();
  }
  if (i < N_NODES) {
    int v = boff[blockIdx.x] + s[t] - d;
    rowptr[i] = v;
    rowcur[i] = v;
  }
  if (i == 0) rowptr[N_NODES] = N_EDGES;
}

__global__ void k_fill(const int* __restrict__ srcA, const int* __restrict__ dstA,
                       int* __restrict__ rowcur, int* __restrict__ colidx) {
  int i = blockIdx.x * blockDim.x + threadIdx.x;
  if (i < N_EDGES) {
    int d = dstA[i];
    int pos = atomicAdd(&rowcur[d], 1);
    colidx[pos] = srcA[i];
  }
}

// ---------------- fused GIN conv layer ----------------
// h_in is bf16 [N][64] (128 B/row = one cache line). Gather: lane =
// (eg = lane>>3, fl = (lane&7)*8): 8 edges x 16B per wave-load, one line
// per edge. Cross-eg reduce via 3 shuffle rounds. GEMMs in fp32 VALU with
// weights streamed from global; one shared sT buffer for t and h1.
template <int APPLY_BN, int EMIT_STATS, int OUT_BF>
__global__ __launch_bounds__(256, 6) void k_conv(
    const ushort* __restrict__ h_in, const float* __restrict__ ss,
    const int* __restrict__ rowptr, const int* __restrict__ colidx,
    const float* __restrict__ w1, const float* __restrict__ b1,
    const float* __restrict__ w2, const float* __restrict__ b2,
    float* __restrict__ h_out_f, ushort* __restrict__ h_out_bf,
    float* __restrict__ stats) {
  __shared__ float sT[64][68];
  __shared__ float sSum[64], sSq[64];

  const int tid = threadIdx.x;
  const int wave = tid >> 6, lane = tid & 63;
  const int eg = lane >> 3;
  const int fl = (lane & 7) << 3;  // first of 8 features
  const int row0 = blockIdx.x * 64;

  if (EMIT_STATS && tid < 64) { sSum[tid] = 0.f; sSq[tid] = 0.f; }

  float sc[8], sh[8];
  if (APPLY_BN) {
    float4 a = ld4(&ss[fl]), b = ld4(&ss[fl + 4]);
    float4 c = ld4(&ss[64 + fl]), d = ld4(&ss[64 + fl + 4]);
    sc[0] = a.x; sc[1] = a.y; sc[2] = a.z; sc[3] = a.w;
    sc[4] = b.x; sc[5] = b.y; sc[6] = b.z; sc[7] = b.w;
    sh[0] = c.x; sh[1] = c.y; sh[2] = c.z; sh[3] = c.w;
    sh[4] = d.x; sh[5] = d.y; sh[6] = d.z; sh[7] = d.w;
  }

#define ACC8(u)                                                        \
  {                                                                    \
    float f0 = __uint_as_float((u).x << 16);                           \
    float f1 = __uint_as_float((u).x & 0xffff0000u);                   \
    float f2 = __uint_as_float((u).y << 16);                           \
    float f3 = __uint_as_float((u).y & 0xffff0000u);                   \
    float f4 = __uint_as_float((u).z << 16);                           \
    float f5 = __uint_as_float((u).z & 0xffff0000u);                   \
    float f6 = __uint_as_float((u).w << 16);                           \
    float f7 = __uint_as_float((u).w & 0xffff0000u);                   \
    if (APPLY_BN) {                                                    \
      f0 = fmaxf(fmaf(f0, sc[0], sh[0]), 0.f);                         \
      f1 = fmaxf(fmaf(f1, sc[1], sh[1]), 0.f);                         \
      f2 = fmaxf(fmaf(f2, sc[2], sh[2]), 0.f);                         \
      f3 = fmaxf(fmaf(f3, sc[3], sh[3]), 0.f);                         \
      f4 = fmaxf(fmaf(f4, sc[4], sh[4]), 0.f);                         \
      f5 = fmaxf(fmaf(f5, sc[5], sh[5]), 0.f);                         \
      f6 = fmaxf(fmaf(f6, sc[6], sh[6]), 0.f);                         \
      f7 = fmaxf(fmaf(f7, sc[7], sh[7]), 0.f);                         \
    }                                                                  \
    acc[0] += f0; acc[1] += f1; acc[2] += f2; acc[3] += f3;            \
    acc[4] += f4; acc[5] += f5; acc[6] += f6; acc[7] += f7;            \
  }

  // ---- phase 1: gather ----
  for (int rr = 0; rr < 16; ++rr) {
    const int r = (wave << 4) + rr;
    const int row = row0 + r;
    float acc[8] = {0.f, 0.f, 0.f, 0.f, 0.f, 0.f, 0.f, 0.f};
    if (row < N_NODES) {  // wave-uniform
      if (eg == 0) {
        uint4 u = *(const uint4*)(h_in + ((size_t)row << 6) + fl);
        ACC8(u);
      }
      const int e0 = rowptr[row], e1 = rowptr[row + 1];
      int e = e0 + eg;
      for (; e + 8 < e1; e += 16) {
        int s0 = colidx[e];
        int s1 = colidx[e + 8];
        uint4 u0 = *(const uint4*)(h_in + ((size_t)s0 << 6) + fl);
        uint4 u1 = *(const uint4*)(h_in + ((size_t)s1 << 6) + fl);
        ACC8(u0);
        ACC8(u1);
      }
      if (e < e1) {
        int s0 = colidx[e];
        uint4 u0 = *(const uint4*)(h_in + ((size_t)s0 << 6) + fl);
        ACC8(u0);
      }
      // reduce across the 8 edge-groups
#pragma unroll
      for (int j = 0; j < 8; ++j) {
        acc[j] += __shfl_xor(acc[j], 8);
        acc[j] += __shfl_xor(acc[j], 16);
        acc[j] += __shfl_xor(acc[j], 32);
      }
    }
    if (lane < 8) {
      *(float4*)&sT[r][fl] = make_float4(acc[0], acc[1], acc[2], acc[3]);
      *(float4*)&sT[r][fl + 4] = make_float4(acc[4], acc[5], acc[6], acc[7]);
    }
  }
#undef ACC8
  __syncthreads();

  const int tc = tid & 15, tr = tid >> 4;  // output cols 4*tc.., rows 4*tr..

  // ---- GEMM1: h1 = relu(t @ w1 + b1), accumulate in regs, write back to sT ----
  float hreg[4][4];
  {
    float acc[4][4];
#pragma unroll
    for (int i = 0; i < 4; ++i)
#pragma unroll
      for (int j = 0; j < 4; ++j) acc[i][j] = 0.f;
#pragma unroll 8
    for (int k = 0; k < 64; ++k) {
      const float4 b = ld4(&w1[(k << 6) + (tc << 2)]);
#pragma unroll
      for (int i = 0; i < 4; ++i) {
        const float a = sT[(tr << 2) + i][k];
        acc[i][0] = fmaf(a, b.x, acc[i][0]);
        acc[i][1] = fmaf(a, b.y, acc[i][1]);
        acc[i][2] = fmaf(a, b.z, acc[i][2]);
        acc[i][3] = fmaf(a, b.w, acc[i][3]);
      }
    }
    const float4 bb = ld4(&b1[tc << 2]);
#pragma unroll
    for (int i = 0; i < 4; ++i) {
      hreg[i][0] = fmaxf(acc[i][0] + bb.x, 0.f);
      hreg[i][1] = fmaxf(acc[i][1] + bb.y, 0.f);
      hreg[i][2] = fmaxf(acc[i][2] + bb.z, 0.f);
      hreg[i][3] = fmaxf(acc[i][3] + bb.w, 0.f);
    }
  }
  __syncthreads();
#pragma unroll
  for (int i = 0; i < 4; ++i)
    *(float4*)&sT[(tr << 2) + i][tc << 2] = *(float4*)&hreg[i][0];
  __syncthreads();

  // ---- GEMM2: h2 = h1 @ w2 + b2 -> global (+ BN stats) ----
  {
    float acc[4][4];
#pragma unroll
    for (int i = 0; i < 4; ++i)
#pragma unroll
      for (int j = 0; j < 4; ++j) acc[i][j] = 0.f;
#pragma unroll 8
    for (int k = 0; k < 64; ++k) {
      const float4 b = ld4(&w2[(k << 6) + (tc << 2)]);
#pragma unroll
      for (int i = 0; i < 4; ++i) {
        const float a = sT[(tr << 2) + i][k];
        acc[i][0] = fmaf(a, b.x, acc[i][0]);
        acc[i][1] = fmaf(a, b.y, acc[i][1]);
        acc[i][2] = fmaf(a, b.z, acc[i][2]);
        acc[i][3] = fmaf(a, b.w, acc[i][3]);
      }
    }
    const float4 bb = ld4(&b2[tc << 2]);
    float p[4] = {0.f, 0.f, 0.f, 0.f}, q[4] = {0.f, 0.f, 0.f, 0.f};
#pragma unroll
    for (int i = 0; i < 4; ++i) {
      const int row = row0 + (tr << 2) + i;
      float4 o;
      o.x = acc[i][0] + bb.x;
      o.y = acc[i][1] + bb.y;
      o.z = acc[i][2] + bb.z;
      o.w = acc[i][3] + bb.w;
      if (row < N_NODES) {
        if (OUT_BF) {
          uint2 o2;
          o2.x = f2bf(o.x) | (f2bf(o.y) << 16);
          o2.y = f2bf(o.z) | (f2bf(o.w) << 16);
          *(uint2*)(h_out_bf + ((size_t)row << 6) + (tc << 2)) = o2;
        } else {
          *(float4*)&h_out_f[row * 64 + (tc << 2)] = o;
        }
        if (EMIT_STATS) {
          p[0] += o.x; q[0] += o.x * o.x;
          p[1] += o.y; q[1] += o.y * o.y;
          p[2] += o.z; q[2] += o.z * o.z;
          p[3] += o.w; q[3] += o.w * o.w;
        }
      }
    }
    if (EMIT_STATS) {
#pragma unroll
      for (int j = 0; j < 4; ++j) {
        atomicAdd(&sSum[(tc << 2) + j], p[j]);
        atomicAdd(&sSq[(tc << 2) + j], q[j]);
      }
      __syncthreads();
      if (tid < 64) {
        atomicAdd(&stats[tid], sSum[tid]);
        atomicAdd(&stats[64 + tid], sSq[tid]);
      }
    }
  }
}

__global__ void k_bnfin(const float* __restrict__ stats, const float* __restrict__ gamma,
                        const float* __restrict__ beta, float* __restrict__ ss) {
  int t = threadIdx.x;
  if (t < 64) {
    const float inv_n = 1.f / (float)N_NODES;
    float mean = stats[t] * inv_n;
    float var = stats[64 + t] * inv_n - mean * mean;
    float scale = gamma[t] * rsqrtf(var + BN_EPS);
    ss[t] = scale;
    ss[64 + t] = beta[t] - mean * scale;
  }
}

// ---------------- global add pool (batch sorted) ----------------
__global__ __launch_bounds__(256) void k_pool(const float* __restrict__ h,
                                              const int* __restrict__ batch,
                                              float* __restrict__ emb) {
  const int NW = 1024;  // total waves
  const int RPW = (N_NODES + NW - 1) / NW;
  int wid = (blockIdx.x * 256 + threadIdx.x) >> 6;
  int lane = threadIdx.x & 63;
  int r0 = wid * RPW;
  if (r0 >= N_NODES) return;
  int r1 = min(r0 + RPW, N_NODES);
  float acc = 0.f;
  int curg = batch[r0];
  for (int i = r0; i < r1; ++i) {
    int g = batch[i];
    if (g != curg) {
      atomicAdd(&emb[curg * 64 + lane], acc);
      acc = 0.f;
      curg = g;
    }
    acc += h[i * 64 + lane];
  }
  atomicAdd(&emb[curg * 64 + lane], acc);
}

// ---------------- final MLP ----------------
__global__ __launch_bounds__(256) void k_mlp(const float* __restrict__ emb,
                                             const float* __restrict__ w1,
                                             const float* __restrict__ b1,
                                             const float* __restrict__ w2,
                                             const float* __restrict__ b2,
                                             float* __restrict__ out) {
  __shared__ float sp[64];
  __shared__ float smid[256];
  int g = blockIdx.x, t = threadIdx.x;
  if (t < 64) sp[t] = emb[g * 64 + t];
  __syncthreads();
  float acc = b1[t];
#pragma unroll 8
  for (int k = 0; k < 64; ++k) acc = fmaf(sp[k], w1[k * 256 + t], acc);
  smid[t] = fmaxf(acc, 0.f);
  __syncthreads();
  if (t < 128) {
    float o = b2[t];
#pragma unroll 8
    for (int k = 0; k < 256; ++k) o = fmaf(smid[k], w2[k * 128 + t], o);
    out[g * 128 + t] = o;
  }
}

extern "C" void kernel_launch(void* const* d_in, const int* in_sizes, int n_in,
                              void* d_out, int out_size, void* d_ws, size_t ws_size,
                              hipStream_t stream) {
  const float* x = (const float*)d_in[0];
  const int* edge = (const int*)d_in[1];
  const int* batch = (const int*)d_in[2];
  const float* cw1[3] = {(const float*)d_in[3], (const float*)d_in[7], (const float*)d_in[11]};
  const float* cb1[3] = {(const float*)d_in[4], (const float*)d_in[8], (const float*)d_in[12]};
  const float* cw2[3] = {(const float*)d_in[5], (const float*)d_in[9], (const float*)d_in[13]};
  const float* cb2[3] = {(const float*)d_in[6], (const float*)d_in[10], (const float*)d_in[14]};
  const float* bng[2] = {(const float*)d_in[15], (const float*)d_in[17]};
  const float* bnb[2] = {(const float*)d_in[16], (const float*)d_in[18]};
  const float* mpw1 = (const float*)d_in[19];
  const float* mpb1 = (const float*)d_in[20];
  const float* mpw2 = (const float*)d_in[21];
  const float* mpb2 = (const float*)d_in[22];

  char* ws = (char*)d_ws;
  size_t off = 0;
  auto alloc = [&](size_t bytes) {
    void* p = ws + off;
    off = (off + bytes + 255) & ~(size_t)255;
    return p;
  };
  int* rowptr = (int*)alloc((N_NODES + 1) * sizeof(int));
  int* rowcur = (int*)alloc(N_NODES * sizeof(int));
  int* colidx = (int*)alloc(N_EDGES * sizeof(int));
  int* bsum = (int*)alloc(512 * sizeof(int));
  int* boff = (int*)alloc(512 * sizeof(int));
  // x_bf and hA_bf are contiguous (each 12.8 MB, 256-aligned); after layer 1
  // both are dead and their combined 25.6 MB is reused as the fp32 layer-2
  // output hF.
  ushort* x_bf = (ushort*)alloc((size_t)N_NODES * 64 * sizeof(ushort));
  ushort* hA_bf = (ushort*)alloc((size_t)N_NODES * 64 * sizeof(ushort));
  ushort* hB_bf = (ushort*)alloc((size_t)N_NODES * 64 * sizeof(ushort));
  float* stats = (float*)alloc(2 * 128 * sizeof(float));
  float* ssbuf = (float*)alloc(2 * 128 * sizeof(float));
  float* hF = (float*)x_bf;

  float* outp = (float*)d_out;
  float* emb = outp + N_GRAPHS * D_OUT;  // output 1 lives right after output 0

  const int* srcA = edge;
  const int* dstA = edge + N_EDGES;

  hipMemsetAsync(rowcur, 0, N_NODES * sizeof(int), stream);
  hipMemsetAsync(stats, 0, 2 * 128 * sizeof(float), stream);
  hipMemsetAsync(emb, 0, N_GRAPHS * 64 * sizeof(float), stream);

  const int NB = (N_NODES + 255) / 256;   // 391
  const int EB = (N_EDGES + 255) / 256;   // 6250
  k_cvt<<<(N_NODES * 64 / 8 + 255) / 256, 256, 0, stream>>>(x, x_bf, N_NODES * 64 / 8);
  k_count<<<EB, 256, 0, stream>>>(dstA, rowcur);
  k_blocksum<<<NB, 256, 0, stream>>>(rowcur, bsum);
  k_scanblocks<<<1, 512, 0, stream>>>(bsum, boff, NB);
  k_scanfinal<<<NB, 256, 0, stream>>>(rowcur, boff, rowptr, rowcur);
  k_fill<<<EB, 256, 0, stream>>>(srcA, dstA, rowcur, colidx);

  const int GC = (N_NODES + 63) / 64;  // 1563
  // layer 0: input x_bf (no BN on input), emit stats0, bf16 out
  k_conv<0, 1, 1><<<GC, 256, 0, stream>>>(x_bf, nullptr, rowptr, colidx, cw1[0], cb1[0],
                                          cw2[0], cb2[0], nullptr, hA_bf, stats);
  k_bnfin<<<1, 64, 0, stream>>>(stats, bng[0], bnb[0], ssbuf);
  // layer 1: input hA_bf with BN0+relu on the fly, emit stats1, bf16 out
  k_conv<1, 1, 1><<<GC, 256, 0, stream>>>(hA_bf, ssbuf, rowptr, colidx, cw1[1], cb1[1],
                                          cw2[1], cb2[1], nullptr, hB_bf, stats + 128);
  k_bnfin<<<1, 64, 0, stream>>>(stats + 128, bng[1], bnb[1], ssbuf + 128);
  // layer 2: input hB_bf with BN1+relu, fp32 out for pooling
  k_conv<1, 0, 0><<<GC, 256, 0, stream>>>(hB_bf, ssbuf + 128, rowptr, colidx, cw1[2],
                                          cb1[2], cw2[2], cb2[2], hF, nullptr, nullptr);

  k_pool<<<256, 256, 0, stream>>>(hF, batch, emb);
  k_mlp<<<N_GRAPHS, 256, 0, stream>>>(emb, mpw1, mpb1, mpw2, mpb2, outp);
}

// Round 4
// 533.973 us; speedup vs baseline: 1.6159x; 1.0074x over previous
//
#include <hip/hip_runtime.h>

#define N_NODES 100000
#define N_EDGES 1600000
#define D 64
#define N_GRAPHS 64
#define D_LIN 256
#define D_OUT 128
#define BN_EPS 1e-5f
#define NBUCK 782  // ceil(100000/128), bucket = dst>>7 (128-node ranges)
#define BIN_CH 16384

typedef unsigned short ushort;
typedef unsigned int uint;

__device__ __forceinline__ float4 ld4(const float* p) { return *(const float4*)p; }

__device__ __forceinline__ uint f2bf(float f) {
  uint u = __float_as_uint(f);
  return (u + 0x7FFFu + ((u >> 16) & 1u)) >> 16;  // RNE
}

// ---------------- x -> bf16 prepass ----------------
__global__ __launch_bounds__(256) void k_cvt(const float* __restrict__ in,
                                             ushort* __restrict__ out, int n8) {
  int i = blockIdx.x * 256 + threadIdx.x;
  if (i < n8) {
    float4 a = ((const float4*)in)[2 * i];
    float4 b = ((const float4*)in)[2 * i + 1];
    uint4 o;
    o.x = f2bf(a.x) | (f2bf(a.y) << 16);
    o.y = f2bf(a.z) | (f2bf(a.w) << 16);
    o.z = f2bf(b.x) | (f2bf(b.y) << 16);
    o.w = f2bf(b.z) | (f2bf(b.w) << 16);
    ((uint4*)out)[i] = o;
  }
}

// ---------------- CSR build: bucketed counting sort ----------------
// Bucket b covers nodes [b*128, (b+1)*128). Since buckets are contiguous
// node ranges, scanned bucket counts give rowptr at bucket granularity;
// k_bucket fills in the per-node remainder. All colidx writes coalesced.

__global__ __launch_bounds__(256) void k_hist(const int* __restrict__ dstA,
                                              int* __restrict__ bcnt) {
  __shared__ int lh[NBUCK];
  for (int i = threadIdx.x; i < NBUCK; i += 256) lh[i] = 0;
  __syncthreads();
  int i = blockIdx.x * 256 + threadIdx.x;
  const int stride = gridDim.x * 256;
  for (; i < N_EDGES; i += stride) atomicAdd(&lh[dstA[i] >> 7], 1);
  __syncthreads();
  for (int i = threadIdx.x; i < NBUCK; i += 256)
    if (lh[i]) atomicAdd(&bcnt[i], lh[i]);
}

__global__ __launch_bounds__(1024) void k_bscan(const int* __restrict__ bcnt,
                                                int* __restrict__ boff,
                                                int* __restrict__ bcur) {
  __shared__ int s[1024];
  int t = threadIdx.x;
  int v = (t < NBUCK) ? bcnt[t] : 0;
  s[t] = v;
  __syncthreads();
  for (int off = 1; off < 1024; off <<= 1) {
    int u = (t >= off) ? s[t - off] : 0;
    __syncthreads();
    s[t] += u;
    __syncthreads();
  }
  if (t < NBUCK) {
    boff[t] = s[t] - v;  // exclusive
    bcur[t] = s[t] - v;
  }
}

// bin edges into bucket-major pair array; per-block run reservation keeps
// the scatter writes in ~contiguous runs.
__global__ __launch_bounds__(256) void k_bin(const int* __restrict__ srcA,
                                             const int* __restrict__ dstA,
                                             int* __restrict__ bcur,
                                             uint2* __restrict__ pairs) {
  __shared__ int lh[NBUCK];
  __shared__ int lbase[NBUCK];
  const int tid = threadIdx.x;
  for (int i = tid; i < NBUCK; i += 256) lh[i] = 0;
  __syncthreads();
  const int e0 = blockIdx.x * BIN_CH;
  const int e1 = min(e0 + BIN_CH, N_EDGES);
  for (int i = e0 + tid; i < e1; i += 256) atomicAdd(&lh[dstA[i] >> 7], 1);
  __syncthreads();
  for (int b = tid; b < NBUCK; b += 256) {
    int c = lh[b];
    if (c) lbase[b] = atomicAdd(&bcur[b], c);
  }
  __syncthreads();
  for (int b = tid; b < NBUCK; b += 256) lh[b] = 0;
  __syncthreads();
  for (int i = e0 + tid; i < e1; i += 256) {
    int d = dstA[i];
    int b = d >> 7;
    int p = lbase[b] + atomicAdd(&lh[b], 1);
    pairs[p] = make_uint2((uint)srcA[i], (uint)d);
  }
}

// one block per bucket: local degree+scan -> rowptr slice; LDS-staged sort
// -> coalesced colidx flush.
__global__ __launch_bounds__(256) void k_bucket(const uint2* __restrict__ pairs,
                                                const int* __restrict__ boff,
                                                const int* __restrict__ bcnt,
                                                int* __restrict__ rowptr,
                                                int* __restrict__ colidx) {
  __shared__ int ldeg[128], lsc[128], lcur[128];
  __shared__ int stage[4096];
  const int tid = threadIdx.x;
  const int b = blockIdx.x;
  const int node0 = b << 7;
  const int base = boff[b], cnt = bcnt[b];
  if (tid < 128) ldeg[tid] = 0;
  __syncthreads();
  for (int i = tid; i < cnt; i += 256) atomicAdd(&ldeg[pairs[base + i].y & 127], 1);
  __syncthreads();
  if (tid < 128) lsc[tid] = ldeg[tid];
  __syncthreads();
  for (int off = 1; off < 128; off <<= 1) {
    int u = (tid < 128 && tid >= off) ? lsc[tid - off] : 0;
    __syncthreads();
    if (tid < 128) lsc[tid] += u;
    __syncthreads();
  }
  if (tid < 128) {
    int excl = lsc[tid] - ldeg[tid];
    lcur[tid] = excl;
    int node = node0 + tid;
    if (node < N_NODES) rowptr[node] = base + excl;
  }
  if (b == NBUCK - 1 && tid == 0) rowptr[N_NODES] = N_EDGES;
  __syncthreads();
  if (cnt <= 4096) {
    for (int i = tid; i < cnt; i += 256) {
      uint2 pr = pairs[base + i];
      int p = atomicAdd(&lcur[pr.y & 127], 1);
      stage[p] = (int)pr.x;
    }
    __syncthreads();
    for (int i = tid; i < cnt; i += 256) colidx[base + i] = stage[i];
  } else {  // safety fallback, statistically never taken
    for (int i = tid; i < cnt; i += 256) {
      uint2 pr = pairs[base + i];
      int p = atomicAdd(&lcur[pr.y & 127], 1);
      colidx[base + p] = (int)pr.x;
    }
  }
}

// ---------------- fused GIN conv layer ----------------
// 32-row tile, 128 threads (2 waves) -> 3125 blocks, ~9 KB LDS, high
// occupancy for the latency-bound gather. h_in bf16 (128 B/row = 1 line).
// Gather lanes: eg = lane>>3 (8 edge groups), fl = (lane&7)*8 features.
template <int APPLY_BN, int EMIT_STATS, int OUT_BF>
__global__ __launch_bounds__(128, 8) void k_conv(
    const ushort* __restrict__ h_in, const float* __restrict__ ss,
    const int* __restrict__ rowptr, const int* __restrict__ colidx,
    const float* __restrict__ w1, const float* __restrict__ b1,
    const float* __restrict__ w2, const float* __restrict__ b2,
    float* __restrict__ h_out_f, ushort* __restrict__ h_out_bf,
    float* __restrict__ stats) {
  __shared__ float sT[32][68];
  __shared__ float sSum[64], sSq[64];

  const int tid = threadIdx.x;
  const int wave = tid >> 6, lane = tid & 63;
  const int eg = lane >> 3;
  const int fl = (lane & 7) << 3;  // first of 8 features
  const int row0 = blockIdx.x * 32;

  if (EMIT_STATS && tid < 64) { sSum[tid] = 0.f; sSq[tid] = 0.f; }

  float sc[8], sh[8];
  if (APPLY_BN) {
    float4 a = ld4(&ss[fl]), b = ld4(&ss[fl + 4]);
    float4 c = ld4(&ss[64 + fl]), d = ld4(&ss[64 + fl + 4]);
    sc[0] = a.x; sc[1] = a.y; sc[2] = a.z; sc[3] = a.w;
    sc[4] = b.x; sc[5] = b.y; sc[6] = b.z; sc[7] = b.w;
    sh[0] = c.x; sh[1] = c.y; sh[2] = c.z; sh[3] = c.w;
    sh[4] = d.x; sh[5] = d.y; sh[6] = d.z; sh[7] = d.w;
  }

#define ACC8(u)                                                        \
  {                                                                    \
    float f0 = __uint_as_float((u).x << 16);                           \
    float f1 = __uint_as_float((u).x & 0xffff0000u);                   \
    float f2 = __uint_as_float((u).y << 16);                           \
    float f3 = __uint_as_float((u).y & 0xffff0000u);                   \
    float f4 = __uint_as_float((u).z << 16);                           \
    float f5 = __uint_as_float((u).z & 0xffff0000u);                   \
    float f6 = __uint_as_float((u).w << 16);                           \
    float f7 = __uint_as_float((u).w & 0xffff0000u);                   \
    if (APPLY_BN) {                                                    \
      f0 = fmaxf(fmaf(f0, sc[0], sh[0]), 0.f);                         \
      f1 = fmaxf(fmaf(f1, sc[1], sh[1]), 0.f);                         \
      f2 = fmaxf(fmaf(f2, sc[2], sh[2]), 0.f);                         \
      f3 = fmaxf(fmaf(f3, sc[3], sh[3]), 0.f);                         \
      f4 = fmaxf(fmaf(f4, sc[4], sh[4]), 0.f);                         \
      f5 = fmaxf(fmaf(f5, sc[5], sh[5]), 0.f);                         \
      f6 = fmaxf(fmaf(f6, sc[6], sh[6]), 0.f);                         \
      f7 = fmaxf(fmaf(f7, sc[7], sh[7]), 0.f);                         \
    }                                                                  \
    acc[0] += f0; acc[1] += f1; acc[2] += f2; acc[3] += f3;            \
    acc[4] += f4; acc[5] += f5; acc[6] += f6; acc[7] += f7;            \
  }

  // ---- phase 1: gather (grid is exact: 3125*32 == N_NODES) ----
  for (int rr = 0; rr < 16; ++rr) {
    const int r = (wave << 4) + rr;
    const int row = row0 + r;
    float acc[8] = {0.f, 0.f, 0.f, 0.f, 0.f, 0.f, 0.f, 0.f};
    if (eg == 0) {
      uint4 u = *(const uint4*)(h_in + ((size_t)row << 6) + fl);
      ACC8(u);
    }
    const int e0 = rowptr[row], e1 = rowptr[row + 1];
    int e = e0 + eg;
    for (; e + 8 < e1; e += 16) {
      int s0 = colidx[e];
      int s1 = colidx[e + 8];
      uint4 u0 = *(const uint4*)(h_in + ((size_t)s0 << 6) + fl);
      uint4 u1 = *(const uint4*)(h_in + ((size_t)s1 << 6) + fl);
      ACC8(u0);
      ACC8(u1);
    }
    if (e < e1) {
      int s0 = colidx[e];
      uint4 u0 = *(const uint4*)(h_in + ((size_t)s0 << 6) + fl);
      ACC8(u0);
    }
    // reduce across the 8 edge-groups
#pragma unroll
    for (int j = 0; j < 8; ++j) {
      acc[j] += __shfl_xor(acc[j], 8);
      acc[j] += __shfl_xor(acc[j], 16);
      acc[j] += __shfl_xor(acc[j], 32);
    }
    if (lane < 8) {
      *(float4*)&sT[r][fl] = make_float4(acc[0], acc[1], acc[2], acc[3]);
      *(float4*)&sT[r][fl + 4] = make_float4(acc[4], acc[5], acc[6], acc[7]);
    }
  }
#undef ACC8
  __syncthreads();

  const int tc = tid & 15, tr = tid >> 4;  // cols 4*tc.., rows 4*tr.. (tr 0..7)

  // ---- GEMM1: h1 = relu(t @ w1 + b1), regs, write back to sT ----
  float hreg[4][4];
  {
    float acc[4][4];
#pragma unroll
    for (int i = 0; i < 4; ++i)
#pragma unroll
      for (int j = 0; j < 4; ++j) acc[i][j] = 0.f;
#pragma unroll 8
    for (int k = 0; k < 64; ++k) {
      const float4 b = ld4(&w1[(k << 6) + (tc << 2)]);
#pragma unroll
      for (int i = 0; i < 4; ++i) {
        const float a = sT[(tr << 2) + i][k];
        acc[i][0] = fmaf(a, b.x, acc[i][0]);
        acc[i][1] = fmaf(a, b.y, acc[i][1]);
        acc[i][2] = fmaf(a, b.z, acc[i][2]);
        acc[i][3] = fmaf(a, b.w, acc[i][3]);
      }
    }
    const float4 bb = ld4(&b1[tc << 2]);
#pragma unroll
    for (int i = 0; i < 4; ++i) {
      hreg[i][0] = fmaxf(acc[i][0] + bb.x, 0.f);
      hreg[i][1] = fmaxf(acc[i][1] + bb.y, 0.f);
      hreg[i][2] = fmaxf(acc[i][2] + bb.z, 0.f);
      hreg[i][3] = fmaxf(acc[i][3] + bb.w, 0.f);
    }
  }
  __syncthreads();
#pragma unroll
  for (int i = 0; i < 4; ++i)
    *(float4*)&sT[(tr << 2) + i][tc << 2] = *(float4*)&hreg[i][0];
  __syncthreads();

  // ---- GEMM2: h2 = h1 @ w2 + b2 -> global (+ BN stats) ----
  {
    float acc[4][4];
#pragma unroll
    for (int i = 0; i < 4; ++i)
#pragma unroll
      for (int j = 0; j < 4; ++j) acc[i][j] = 0.f;
#pragma unroll 8
    for (int k = 0; k < 64; ++k) {
      const float4 b = ld4(&w2[(k << 6) + (tc << 2)]);
#pragma unroll
      for (int i = 0; i < 4; ++i) {
        const float a = sT[(tr << 2) + i][k];
        acc[i][0] = fmaf(a, b.x, acc[i][0]);
        acc[i][1] = fmaf(a, b.y, acc[i][1]);
        acc[i][2] = fmaf(a, b.z, acc[i][2]);
        acc[i][3] = fmaf(a, b.w, acc[i][3]);
      }
    }
    const float4 bb = ld4(&b2[tc << 2]);
    float p[4] = {0.f, 0.f, 0.f, 0.f}, q[4] = {0.f, 0.f, 0.f, 0.f};
#pragma unroll
    for (int i = 0; i < 4; ++i) {
      const int row = row0 + (tr << 2) + i;
      float4 o;
      o.x = acc[i][0] + bb.x;
      o.y = acc[i][1] + bb.y;
      o.z = acc[i][2] + bb.z;
      o.w = acc[i][3] + bb.w;
      if (OUT_BF) {
        uint2 o2;
        o2.x = f2bf(o.x) | (f2bf(o.y) << 16);
        o2.y = f2bf(o.z) | (f2bf(o.w) << 16);
        *(uint2*)(h_out_bf + ((size_t)row << 6) + (tc << 2)) = o2;
      } else {
        *(float4*)&h_out_f[row * 64 + (tc << 2)] = o;
      }
      if (EMIT_STATS) {
        p[0] += o.x; q[0] += o.x * o.x;
        p[1] += o.y; q[1] += o.y * o.y;
        p[2] += o.z; q[2] += o.z * o.z;
        p[3] += o.w; q[3] += o.w * o.w;
      }
    }
    if (EMIT_STATS) {
#pragma unroll
      for (int j = 0; j < 4; ++j) {
        atomicAdd(&sSum[(tc << 2) + j], p[j]);
        atomicAdd(&sSq[(tc << 2) + j], q[j]);
      }
      __syncthreads();
      if (tid < 64) {
        atomicAdd(&stats[tid], sSum[tid]);
        atomicAdd(&stats[64 + tid], sSq[tid]);
      }
    }
  }
}

__global__ void k_bnfin(const float* __restrict__ stats, const float* __restrict__ gamma,
                        const float* __restrict__ beta, float* __restrict__ ss) {
  int t = threadIdx.x;
  if (t < 64) {
    const float inv_n = 1.f / (float)N_NODES;
    float mean = stats[t] * inv_n;
    float var = stats[64 + t] * inv_n - mean * mean;
    float scale = gamma[t] * rsqrtf(var + BN_EPS);
    ss[t] = scale;
    ss[64 + t] = beta[t] - mean * scale;
  }
}

// ---------------- global add pool (batch sorted) ----------------
__global__ __launch_bounds__(256) void k_pool(const float* __restrict__ h,
                                              const int* __restrict__ batch,
                                              float* __restrict__ emb) {
  const int NW = 1024;  // total waves
  const int RPW = (N_NODES + NW - 1) / NW;
  int wid = (blockIdx.x * 256 + threadIdx.x) >> 6;
  int lane = threadIdx.x & 63;
  int r0 = wid * RPW;
  if (r0 >= N_NODES) return;
  int r1 = min(r0 + RPW, N_NODES);
  float acc = 0.f;
  int curg = batch[r0];
  for (int i = r0; i < r1; ++i) {
    int g = batch[i];
    if (g != curg) {
      atomicAdd(&emb[curg * 64 + lane], acc);
      acc = 0.f;
      curg = g;
    }
    acc += h[i * 64 + lane];
  }
  atomicAdd(&emb[curg * 64 + lane], acc);
}

// ---------------- final MLP ----------------
__global__ __launch_bounds__(256) void k_mlp(const float* __restrict__ emb,
                                             const float* __restrict__ w1,
                                             const float* __restrict__ b1,
                                             const float* __restrict__ w2,
                                             const float* __restrict__ b2,
                                             float* __restrict__ out) {
  __shared__ float sp[64];
  __shared__ float smid[256];
  int g = blockIdx.x, t = threadIdx.x;
  if (t < 64) sp[t] = emb[g * 64 + t];
  __syncthreads();
  float acc = b1[t];
#pragma unroll 8
  for (int k = 0; k < 64; ++k) acc = fmaf(sp[k], w1[k * 256 + t], acc);
  smid[t] = fmaxf(acc, 0.f);
  __syncthreads();
  if (t < 128) {
    float o = b2[t];
#pragma unroll 8
    for (int k = 0; k < 256; ++k) o = fmaf(smid[k], w2[k * 128 + t], o);
    out[g * 128 + t] = o;
  }
}

extern "C" void kernel_launch(void* const* d_in, const int* in_sizes, int n_in,
                              void* d_out, int out_size, void* d_ws, size_t ws_size,
                              hipStream_t stream) {
  const float* x = (const float*)d_in[0];
  const int* edge = (const int*)d_in[1];
  const int* batch = (const int*)d_in[2];
  const float* cw1[3] = {(const float*)d_in[3], (const float*)d_in[7], (const float*)d_in[11]};
  const float* cb1[3] = {(const float*)d_in[4], (const float*)d_in[8], (const float*)d_in[12]};
  const float* cw2[3] = {(const float*)d_in[5], (const float*)d_in[9], (const float*)d_in[13]};
  const float* cb2[3] = {(const float*)d_in[6], (const float*)d_in[10], (const float*)d_in[14]};
  const float* bng[2] = {(const float*)d_in[15], (const float*)d_in[17]};
  const float* bnb[2] = {(const float*)d_in[16], (const float*)d_in[18]};
  const float* mpw1 = (const float*)d_in[19];
  const float* mpb1 = (const float*)d_in[20];
  const float* mpw2 = (const float*)d_in[21];
  const float* mpb2 = (const float*)d_in[22];

  char* ws = (char*)d_ws;
  size_t off = 0;
  auto alloc = [&](size_t bytes) {
    void* p = ws + off;
    off = (off + bytes + 255) & ~(size_t)255;
    return p;
  };
  int* rowptr = (int*)alloc((N_NODES + 1) * sizeof(int));
  int* colidx = (int*)alloc(N_EDGES * sizeof(int));
  int* bcnt = (int*)alloc(NBUCK * sizeof(int));
  int* boff = (int*)alloc(NBUCK * sizeof(int));
  int* bcur = (int*)alloc(NBUCK * sizeof(int));
  // x_bf and hA_bf contiguous (12.8 MB each); after layer 1 both are dead and
  // the combined 25.6 MB is reused as the fp32 layer-2 output hF.
  ushort* x_bf = (ushort*)alloc((size_t)N_NODES * 64 * sizeof(ushort));
  ushort* hA_bf = (ushort*)alloc((size_t)N_NODES * 64 * sizeof(ushort));
  ushort* hB_bf = (ushort*)alloc((size_t)N_NODES * 64 * sizeof(ushort));
  float* stats = (float*)alloc(2 * 128 * sizeof(float));
  float* ssbuf = (float*)alloc(2 * 128 * sizeof(float));
  float* hF = (float*)x_bf;
  // pairs (12.8 MB) aliases hB_bf: pairs is dead before layer 1 writes hB_bf.
  uint2* pairs = (uint2*)hB_bf;

  float* outp = (float*)d_out;
  float* emb = outp + N_GRAPHS * D_OUT;  // output 1 lives right after output 0

  const int* srcA = edge;
  const int* dstA = edge + N_EDGES;

  hipMemsetAsync(bcnt, 0, NBUCK * sizeof(int), stream);
  hipMemsetAsync(stats, 0, 2 * 128 * sizeof(float), stream);
  hipMemsetAsync(emb, 0, N_GRAPHS * 64 * sizeof(float), stream);

  k_cvt<<<(N_NODES * 64 / 8 + 255) / 256, 256, 0, stream>>>(x, x_bf, N_NODES * 64 / 8);
  k_hist<<<256, 256, 0, stream>>>(dstA, bcnt);
  k_bscan<<<1, 1024, 0, stream>>>(bcnt, boff, bcur);
  k_bin<<<(N_EDGES + BIN_CH - 1) / BIN_CH, 256, 0, stream>>>(srcA, dstA, bcur, pairs);
  k_bucket<<<NBUCK, 256, 0, stream>>>(pairs, boff, bcnt, rowptr, colidx);

  const int GC = N_NODES / 32;  // 3125, exact
  // layer 0: input x_bf (no BN on input), emit stats0, bf16 out
  k_conv<0, 1, 1><<<GC, 128, 0, stream>>>(x_bf, nullptr, rowptr, colidx, cw1[0], cb1[0],
                                          cw2[0], cb2[0], nullptr, hA_bf, stats);
  k_bnfin<<<1, 64, 0, stream>>>(stats, bng[0], bnb[0], ssbuf);
  // layer 1: input hA_bf with BN0+relu on the fly, emit stats1, bf16 out
  k_conv<1, 1, 1><<<GC, 128, 0, stream>>>(hA_bf, ssbuf, rowptr, colidx, cw1[1], cb1[1],
                                          cw2[1], cb2[1], nullptr, hB_bf, stats + 128);
  k_bnfin<<<1, 64, 0, stream>>>(stats + 128, bng[1], bnb[1], ssbuf + 128);
  // layer 2: input hB_bf with BN1+relu, fp32 out for pooling
  k_conv<1, 0, 0><<<GC, 128, 0, stream>>>(hB_bf, ssbuf + 128, rowptr, colidx, cw1[2],
                                          cb1[2], cw2[2], cb2[2], hF, nullptr, nullptr);

  k_pool<<<256, 256, 0, stream>>>(hF, batch, emb);
  k_mlp<<<N_GRAPHS, 256, 0, stream>>>(emb, mpw1, mpb1, mpw2, mpb2, outp);
}

// Round 5
// 451.400 us; speedup vs baseline: 1.9115x; 1.1829x over previous
//
#include <hip/hip_runtime.h>

#define N_NODES 100000
#define N_EDGES 1600000
#define D 64
#define N_GRAPHS 64
#define D_LIN 256
#define D_OUT 128
#define BN_EPS 1e-5f
#define NBUCK 782  // ceil(100000/128), bucket = dst>>7 (128-node ranges)
#define BIN_CH 16384

typedef unsigned short ushort;
typedef unsigned int uint;

__device__ __forceinline__ float4 ld4(const float* p) { return *(const float4*)p; }

__device__ __forceinline__ uint f2bf(float f) {
  uint u = __float_as_uint(f);
  return (u + 0x7FFFu + ((u >> 16) & 1u)) >> 16;  // RNE
}

// ---------------- x -> bf16 prepass ----------------
__global__ __launch_bounds__(256) void k_cvt(const float* __restrict__ in,
                                             ushort* __restrict__ out, int n8) {
  int i = blockIdx.x * 256 + threadIdx.x;
  if (i < n8) {
    float4 a = ((const float4*)in)[2 * i];
    float4 b = ((const float4*)in)[2 * i + 1];
    uint4 o;
    o.x = f2bf(a.x) | (f2bf(a.y) << 16);
    o.y = f2bf(a.z) | (f2bf(a.w) << 16);
    o.z = f2bf(b.x) | (f2bf(b.y) << 16);
    o.w = f2bf(b.z) | (f2bf(b.w) << 16);
    ((uint4*)out)[i] = o;
  }
}

// ---------------- CSR build: bucketed counting sort ----------------
__global__ __launch_bounds__(256) void k_hist(const int* __restrict__ dstA,
                                              int* __restrict__ bcnt) {
  __shared__ int lh[NBUCK];
  for (int i = threadIdx.x; i < NBUCK; i += 256) lh[i] = 0;
  __syncthreads();
  int i = blockIdx.x * 256 + threadIdx.x;
  const int stride = gridDim.x * 256;
  for (; i < N_EDGES; i += stride) atomicAdd(&lh[dstA[i] >> 7], 1);
  __syncthreads();
  for (int i = threadIdx.x; i < NBUCK; i += 256)
    if (lh[i]) atomicAdd(&bcnt[i], lh[i]);
}

__global__ __launch_bounds__(1024) void k_bscan(const int* __restrict__ bcnt,
                                                int* __restrict__ boff,
                                                int* __restrict__ bcur) {
  __shared__ int s[1024];
  int t = threadIdx.x;
  int v = (t < NBUCK) ? bcnt[t] : 0;
  s[t] = v;
  __syncthreads();
  for (int off = 1; off < 1024; off <<= 1) {
    int u = (t >= off) ? s[t - off] : 0;
    __syncthreads();
    s[t] += u;
    __syncthreads();
  }
  if (t < NBUCK) {
    boff[t] = s[t] - v;  // exclusive
    bcur[t] = s[t] - v;
  }
}

__global__ __launch_bounds__(256) void k_bin(const int* __restrict__ srcA,
                                             const int* __restrict__ dstA,
                                             int* __restrict__ bcur,
                                             uint2* __restrict__ pairs) {
  __shared__ int lh[NBUCK];
  __shared__ int lbase[NBUCK];
  const int tid = threadIdx.x;
  for (int i = tid; i < NBUCK; i += 256) lh[i] = 0;
  __syncthreads();
  const int e0 = blockIdx.x * BIN_CH;
  const int e1 = min(e0 + BIN_CH, N_EDGES);
  for (int i = e0 + tid; i < e1; i += 256) atomicAdd(&lh[dstA[i] >> 7], 1);
  __syncthreads();
  for (int b = tid; b < NBUCK; b += 256) {
    int c = lh[b];
    if (c) lbase[b] = atomicAdd(&bcur[b], c);
  }
  __syncthreads();
  for (int b = tid; b < NBUCK; b += 256) lh[b] = 0;
  __syncthreads();
  for (int i = e0 + tid; i < e1; i += 256) {
    int d = dstA[i];
    int b = d >> 7;
    int p = lbase[b] + atomicAdd(&lh[b], 1);
    pairs[p] = make_uint2((uint)srcA[i], (uint)d);
  }
}

__global__ __launch_bounds__(256) void k_bucket(const uint2* __restrict__ pairs,
                                                const int* __restrict__ boff,
                                                const int* __restrict__ bcnt,
                                                int* __restrict__ rowptr,
                                                int* __restrict__ colidx) {
  __shared__ int ldeg[128], lsc[128], lcur[128];
  __shared__ int stage[4096];
  const int tid = threadIdx.x;
  const int b = blockIdx.x;
  const int node0 = b << 7;
  const int base = boff[b], cnt = bcnt[b];
  if (tid < 128) ldeg[tid] = 0;
  __syncthreads();
  for (int i = tid; i < cnt; i += 256) atomicAdd(&ldeg[pairs[base + i].y & 127], 1);
  __syncthreads();
  if (tid < 128) lsc[tid] = ldeg[tid];
  __syncthreads();
  for (int off = 1; off < 128; off <<= 1) {
    int u = (tid < 128 && tid >= off) ? lsc[tid - off] : 0;
    __syncthreads();
    if (tid < 128) lsc[tid] += u;
    __syncthreads();
  }
  if (tid < 128) {
    int excl = lsc[tid] - ldeg[tid];
    lcur[tid] = excl;
    int node = node0 + tid;
    if (node < N_NODES) rowptr[node] = base + excl;
  }
  if (b == NBUCK - 1 && tid == 0) rowptr[N_NODES] = N_EDGES;
  __syncthreads();
  if (cnt <= 4096) {
    for (int i = tid; i < cnt; i += 256) {
      uint2 pr = pairs[base + i];
      int p = atomicAdd(&lcur[pr.y & 127], 1);
      stage[p] = (int)pr.x;
    }
    __syncthreads();
    for (int i = tid; i < cnt; i += 256) colidx[base + i] = stage[i];
  } else {  // safety fallback, statistically never taken
    for (int i = tid; i < cnt; i += 256) {
      uint2 pr = pairs[base + i];
      int p = atomicAdd(&lcur[pr.y & 127], 1);
      colidx[base + p] = (int)pr.x;
    }
  }
}

// ---------------- fused GIN conv layer ----------------
// 32-row tile, 128 threads. Row-group gather: each wave = 8 row-groups x
// 8 feature-lanes; group g owns one row (128 B bf16 = 8 lanes x 16 B),
// lane accumulates its private 8 features over the row's edges -> NO
// cross-lane reduction. Unroll-4 edge loop keeps up to 32 lines in
// flight per wave.
template <int APPLY_BN, int EMIT_STATS, int OUT_BF>
__global__ __launch_bounds__(128, 6) void k_conv(
    const ushort* __restrict__ h_in, const float* __restrict__ ss,
    const int* __restrict__ rowptr, const int* __restrict__ colidx,
    const float* __restrict__ w1, const float* __restrict__ b1,
    const float* __restrict__ w2, const float* __restrict__ b2,
    float* __restrict__ h_out_f, ushort* __restrict__ h_out_bf,
    float* __restrict__ stats) {
  __shared__ float sT[32][68];
  __shared__ float sSum[64], sSq[64];

  const int tid = threadIdx.x;
  const int wave = tid >> 6, lane = tid & 63;
  const int g = lane >> 3;         // row slot within wave (0..7)
  const int fl = (lane & 7) << 3;  // first of this lane's 8 features
  const int row0 = blockIdx.x * 32;

  if (EMIT_STATS && tid < 64) { sSum[tid] = 0.f; sSq[tid] = 0.f; }

  float sc[8], sh[8];
  if (APPLY_BN) {
    float4 a = ld4(&ss[fl]), b = ld4(&ss[fl + 4]);
    float4 c = ld4(&ss[64 + fl]), d = ld4(&ss[64 + fl + 4]);
    sc[0] = a.x; sc[1] = a.y; sc[2] = a.z; sc[3] = a.w;
    sc[4] = b.x; sc[5] = b.y; sc[6] = b.z; sc[7] = b.w;
    sh[0] = c.x; sh[1] = c.y; sh[2] = c.z; sh[3] = c.w;
    sh[4] = d.x; sh[5] = d.y; sh[6] = d.z; sh[7] = d.w;
  }

#define ACC8(u)                                                        \
  {                                                                    \
    float f0 = __uint_as_float((u).x << 16);                           \
    float f1 = __uint_as_float((u).x & 0xffff0000u);                   \
    float f2 = __uint_as_float((u).y << 16);                           \
    float f3 = __uint_as_float((u).y & 0xffff0000u);                   \
    float f4 = __uint_as_float((u).z << 16);                           \
    float f5 = __uint_as_float((u).z & 0xffff0000u);                   \
    float f6 = __uint_as_float((u).w << 16);                           \
    float f7 = __uint_as_float((u).w & 0xffff0000u);                   \
    if (APPLY_BN) {                                                    \
      f0 = fmaxf(fmaf(f0, sc[0], sh[0]), 0.f);                         \
      f1 = fmaxf(fmaf(f1, sc[1], sh[1]), 0.f);                         \
      f2 = fmaxf(fmaf(f2, sc[2], sh[2]), 0.f);                         \
      f3 = fmaxf(fmaf(f3, sc[3], sh[3]), 0.f);                         \
      f4 = fmaxf(fmaf(f4, sc[4], sh[4]), 0.f);                         \
      f5 = fmaxf(fmaf(f5, sc[5], sh[5]), 0.f);                         \
      f6 = fmaxf(fmaf(f6, sc[6], sh[6]), 0.f);                         \
      f7 = fmaxf(fmaf(f7, sc[7], sh[7]), 0.f);                         \
    }                                                                  \
    acc[0] += f0; acc[1] += f1; acc[2] += f2; acc[3] += f3;            \
    acc[4] += f4; acc[5] += f5; acc[6] += f6; acc[7] += f7;            \
  }

  // ---- phase 1: gather (2 batches of 8 rows per wave; grid exact) ----
#pragma unroll
  for (int b = 0; b < 2; ++b) {
    const int r = (wave << 4) + (b << 3) + g;
    const int row = row0 + r;
    float acc[8] = {0.f, 0.f, 0.f, 0.f, 0.f, 0.f, 0.f, 0.f};
    {  // self term: all 64 lanes load (8 full rows per instruction)
      uint4 u = *(const uint4*)(h_in + ((size_t)row << 6) + fl);
      ACC8(u);
    }
    const int e1 = rowptr[row + 1];
    int e = rowptr[row];
    for (; e + 3 < e1; e += 4) {
      int s0 = colidx[e];
      int s1 = colidx[e + 1];
      int s2 = colidx[e + 2];
      int s3 = colidx[e + 3];
      uint4 u0 = *(const uint4*)(h_in + ((size_t)s0 << 6) + fl);
      uint4 u1 = *(const uint4*)(h_in + ((size_t)s1 << 6) + fl);
      uint4 u2 = *(const uint4*)(h_in + ((size_t)s2 << 6) + fl);
      uint4 u3 = *(const uint4*)(h_in + ((size_t)s3 << 6) + fl);
      ACC8(u0);
      ACC8(u1);
      ACC8(u2);
      ACC8(u3);
    }
    for (; e < e1; ++e) {
      int s0 = colidx[e];
      uint4 u0 = *(const uint4*)(h_in + ((size_t)s0 << 6) + fl);
      ACC8(u0);
    }
    *(float4*)&sT[r][fl] = make_float4(acc[0], acc[1], acc[2], acc[3]);
    *(float4*)&sT[r][fl + 4] = make_float4(acc[4], acc[5], acc[6], acc[7]);
  }
#undef ACC8
  __syncthreads();

  const int tc = tid & 15, tr = tid >> 4;  // cols 4*tc.., rows 4*tr.. (tr 0..7)

  // ---- GEMM1: h1 = relu(t @ w1 + b1), regs, write back to sT ----
  float hreg[4][4];
  {
    float acc[4][4];
#pragma unroll
    for (int i = 0; i < 4; ++i)
#pragma unroll
      for (int j = 0; j < 4; ++j) acc[i][j] = 0.f;
#pragma unroll 8
    for (int k = 0; k < 64; ++k) {
      const float4 b = ld4(&w1[(k << 6) + (tc << 2)]);
#pragma unroll
      for (int i = 0; i < 4; ++i) {
        const float a = sT[(tr << 2) + i][k];
        acc[i][0] = fmaf(a, b.x, acc[i][0]);
        acc[i][1] = fmaf(a, b.y, acc[i][1]);
        acc[i][2] = fmaf(a, b.z, acc[i][2]);
        acc[i][3] = fmaf(a, b.w, acc[i][3]);
      }
    }
    const float4 bb = ld4(&b1[tc << 2]);
#pragma unroll
    for (int i = 0; i < 4; ++i) {
      hreg[i][0] = fmaxf(acc[i][0] + bb.x, 0.f);
      hreg[i][1] = fmaxf(acc[i][1] + bb.y, 0.f);
      hreg[i][2] = fmaxf(acc[i][2] + bb.z, 0.f);
      hreg[i][3] = fmaxf(acc[i][3] + bb.w, 0.f);
    }
  }
  __syncthreads();
#pragma unroll
  for (int i = 0; i < 4; ++i)
    *(float4*)&sT[(tr << 2) + i][tc << 2] = *(float4*)&hreg[i][0];
  __syncthreads();

  // ---- GEMM2: h2 = h1 @ w2 + b2 -> global (+ BN stats) ----
  {
    float acc[4][4];
#pragma unroll
    for (int i = 0; i < 4; ++i)
#pragma unroll
      for (int j = 0; j < 4; ++j) acc[i][j] = 0.f;
#pragma unroll 8
    for (int k = 0; k < 64; ++k) {
      const float4 b = ld4(&w2[(k << 6) + (tc << 2)]);
#pragma unroll
      for (int i = 0; i < 4; ++i) {
        const float a = sT[(tr << 2) + i][k];
        acc[i][0] = fmaf(a, b.x, acc[i][0]);
        acc[i][1] = fmaf(a, b.y, acc[i][1]);
        acc[i][2] = fmaf(a, b.z, acc[i][2]);
        acc[i][3] = fmaf(a, b.w, acc[i][3]);
      }
    }
    const float4 bb = ld4(&b2[tc << 2]);
    float p[4] = {0.f, 0.f, 0.f, 0.f}, q[4] = {0.f, 0.f, 0.f, 0.f};
#pragma unroll
    for (int i = 0; i < 4; ++i) {
      const int row = row0 + (tr << 2) + i;
      float4 o;
      o.x = acc[i][0] + bb.x;
      o.y = acc[i][1] + bb.y;
      o.z = acc[i][2] + bb.z;
      o.w = acc[i][3] + bb.w;
      if (OUT_BF) {
        uint2 o2;
        o2.x = f2bf(o.x) | (f2bf(o.y) << 16);
        o2.y = f2bf(o.z) | (f2bf(o.w) << 16);
        *(uint2*)(h_out_bf + ((size_t)row << 6) + (tc << 2)) = o2;
      } else {
        *(float4*)&h_out_f[row * 64 + (tc << 2)] = o;
      }
      if (EMIT_STATS) {
        p[0] += o.x; q[0] += o.x * o.x;
        p[1] += o.y; q[1] += o.y * o.y;
        p[2] += o.z; q[2] += o.z * o.z;
        p[3] += o.w; q[3] += o.w * o.w;
      }
    }
    if (EMIT_STATS) {
#pragma unroll
      for (int j = 0; j < 4; ++j) {
        atomicAdd(&sSum[(tc << 2) + j], p[j]);
        atomicAdd(&sSq[(tc << 2) + j], q[j]);
      }
      __syncthreads();
      if (tid < 64) {
        atomicAdd(&stats[tid], sSum[tid]);
        atomicAdd(&stats[64 + tid], sSq[tid]);
      }
    }
  }
}

__global__ void k_bnfin(const float* __restrict__ stats, const float* __restrict__ gamma,
                        const float* __restrict__ beta, float* __restrict__ ss) {
  int t = threadIdx.x;
  if (t < 64) {
    const float inv_n = 1.f / (float)N_NODES;
    float mean = stats[t] * inv_n;
    float var = stats[64 + t] * inv_n - mean * mean;
    float scale = gamma[t] * rsqrtf(var + BN_EPS);
    ss[t] = scale;
    ss[64 + t] = beta[t] - mean * scale;
  }
}

// ---------------- global add pool (batch sorted) ----------------
__global__ __launch_bounds__(256) void k_pool(const float* __restrict__ h,
                                              const int* __restrict__ batch,
                                              float* __restrict__ emb) {
  const int NW = 1024;  // total waves
  const int RPW = (N_NODES + NW - 1) / NW;
  int wid = (blockIdx.x * 256 + threadIdx.x) >> 6;
  int lane = threadIdx.x & 63;
  int r0 = wid * RPW;
  if (r0 >= N_NODES) return;
  int r1 = min(r0 + RPW, N_NODES);
  float acc = 0.f;
  int curg = batch[r0];
  for (int i = r0; i < r1; ++i) {
    int g = batch[i];
    if (g != curg) {
      atomicAdd(&emb[curg * 64 + lane], acc);
      acc = 0.f;
      curg = g;
    }
    acc += h[i * 64 + lane];
  }
  atomicAdd(&emb[curg * 64 + lane], acc);
}

// ---------------- final MLP ----------------
__global__ __launch_bounds__(256) void k_mlp(const float* __restrict__ emb,
                                             const float* __restrict__ w1,
                                             const float* __restrict__ b1,
                                             const float* __restrict__ w2,
                                             const float* __restrict__ b2,
                                             float* __restrict__ out) {
  __shared__ float sp[64];
  __shared__ float smid[256];
  int g = blockIdx.x, t = threadIdx.x;
  if (t < 64) sp[t] = emb[g * 64 + t];
  __syncthreads();
  float acc = b1[t];
#pragma unroll 8
  for (int k = 0; k < 64; ++k) acc = fmaf(sp[k], w1[k * 256 + t], acc);
  smid[t] = fmaxf(acc, 0.f);
  __syncthreads();
  if (t < 128) {
    float o = b2[t];
#pragma unroll 8
    for (int k = 0; k < 256; ++k) o = fmaf(smid[k], w2[k * 128 + t], o);
    out[g * 128 + t] = o;
  }
}

extern "C" void kernel_launch(void* const* d_in, const int* in_sizes, int n_in,
                              void* d_out, int out_size, void* d_ws, size_t ws_size,
                              hipStream_t stream) {
  const float* x = (const float*)d_in[0];
  const int* edge = (const int*)d_in[1];
  const int* batch = (const int*)d_in[2];
  const float* cw1[3] = {(const float*)d_in[3], (const float*)d_in[7], (const float*)d_in[11]};
  const float* cb1[3] = {(const float*)d_in[4], (const float*)d_in[8], (const float*)d_in[12]};
  const float* cw2[3] = {(const float*)d_in[5], (const float*)d_in[9], (const float*)d_in[13]};
  const float* cb2[3] = {(const float*)d_in[6], (const float*)d_in[10], (const float*)d_in[14]};
  const float* bng[2] = {(const float*)d_in[15], (const float*)d_in[17]};
  const float* bnb[2] = {(const float*)d_in[16], (const float*)d_in[18]};
  const float* mpw1 = (const float*)d_in[19];
  const float* mpb1 = (const float*)d_in[20];
  const float* mpw2 = (const float*)d_in[21];
  const float* mpb2 = (const float*)d_in[22];

  char* ws = (char*)d_ws;
  size_t off = 0;
  auto alloc = [&](size_t bytes) {
    void* p = ws + off;
    off = (off + bytes + 255) & ~(size_t)255;
    return p;
  };
  int* rowptr = (int*)alloc((N_NODES + 1) * sizeof(int));
  int* colidx = (int*)alloc(N_EDGES * sizeof(int));
  int* bcnt = (int*)alloc(NBUCK * sizeof(int));
  int* boff = (int*)alloc(NBUCK * sizeof(int));
  int* bcur = (int*)alloc(NBUCK * sizeof(int));
  // x_bf and hA_bf contiguous (12.8 MB each); after layer 1 both are dead and
  // the combined 25.6 MB is reused as the fp32 layer-2 output hF.
  ushort* x_bf = (ushort*)alloc((size_t)N_NODES * 64 * sizeof(ushort));
  ushort* hA_bf = (ushort*)alloc((size_t)N_NODES * 64 * sizeof(ushort));
  ushort* hB_bf = (ushort*)alloc((size_t)N_NODES * 64 * sizeof(ushort));
  float* stats = (float*)alloc(2 * 128 * sizeof(float));
  float* ssbuf = (float*)alloc(2 * 128 * sizeof(float));
  float* hF = (float*)x_bf;
  // pairs (12.8 MB) aliases hB_bf: pairs is dead before layer 1 writes hB_bf.
  uint2* pairs = (uint2*)hB_bf;

  float* outp = (float*)d_out;
  float* emb = outp + N_GRAPHS * D_OUT;  // output 1 lives right after output 0

  const int* srcA = edge;
  const int* dstA = edge + N_EDGES;

  hipMemsetAsync(bcnt, 0, NBUCK * sizeof(int), stream);
  hipMemsetAsync(stats, 0, 2 * 128 * sizeof(float), stream);
  hipMemsetAsync(emb, 0, N_GRAPHS * 64 * sizeof(float), stream);

  k_cvt<<<(N_NODES * 64 / 8 + 255) / 256, 256, 0, stream>>>(x, x_bf, N_NODES * 64 / 8);
  k_hist<<<256, 256, 0, stream>>>(dstA, bcnt);
  k_bscan<<<1, 1024, 0, stream>>>(bcnt, boff, bcur);
  k_bin<<<(N_EDGES + BIN_CH - 1) / BIN_CH, 256, 0, stream>>>(srcA, dstA, bcur, pairs);
  k_bucket<<<NBUCK, 256, 0, stream>>>(pairs, boff, bcnt, rowptr, colidx);

  const int GC = N_NODES / 32;  // 3125, exact
  // layer 0: input x_bf (no BN on input), emit stats0, bf16 out
  k_conv<0, 1, 1><<<GC, 128, 0, stream>>>(x_bf, nullptr, rowptr, colidx, cw1[0], cb1[0],
                                          cw2[0], cb2[0], nullptr, hA_bf, stats);
  k_bnfin<<<1, 64, 0, stream>>>(stats, bng[0], bnb[0], ssbuf);
  // layer 1: input hA_bf with BN0+relu on the fly, emit stats1, bf16 out
  k_conv<1, 1, 1><<<GC, 128, 0, stream>>>(hA_bf, ssbuf, rowptr, colidx, cw1[1], cb1[1],
                                          cw2[1], cb2[1], nullptr, hB_bf, stats + 128);
  k_bnfin<<<1, 64, 0, stream>>>(stats + 128, bng[1], bnb[1], ssbuf + 128);
  // layer 2: input hB_bf with BN1+relu, fp32 out for pooling
  k_conv<1, 0, 0><<<GC, 128, 0, stream>>>(hB_bf, ssbuf + 128, rowptr, colidx, cw1[2],
                                          cb1[2], cw2[2], cb2[2], hF, nullptr, nullptr);

  k_pool<<<256, 256, 0, stream>>>(hF, batch, emb);
  k_mlp<<<N_GRAPHS, 256, 0, stream>>>(emb, mpw1, mpb1, mpw2, mpb2, outp);
}